// Round 1
// baseline (314.545 us; speedup 1.0000x reference)
//
#include <hip/hip_runtime.h>
#include <hip/hip_bf16.h>

#define Bq 4
#define Tq 2048
#define Sq 2048
#define Hq 16
#define Dq 64
#define QBLK 64
#define KVBLK 64

typedef short bf16x8 __attribute__((ext_vector_type(8)));
typedef float f32x4 __attribute__((ext_vector_type(4)));

static __device__ __forceinline__ short f2bf(float x) {
    unsigned u = __float_as_uint(x);
    u += 0x7fff + ((u >> 16) & 1);   // round-to-nearest-even
    return (short)(u >> 16);
}

__global__ __launch_bounds__(256, 4) void fattn_fwd(
    const float* __restrict__ q, const float* __restrict__ kv,
    float* __restrict__ out)
{
    // LDS tiles, bf16, row stride 128B, 16B-slot XOR swizzle for bank spread
    __shared__ short Kl[KVBLK * 64];     // [kv][d]
    __shared__ short Vt[64 * KVBLK];     // [d][kv]  (transposed V)
    __shared__ short Pl[4][16 * 64];     // per-wave [q][kv]

    const int tid  = threadIdx.x;
    const int lane = tid & 63;
    const int wid  = tid >> 6;
    const int c    = lane & 15;          // MFMA col index
    const int g    = lane >> 4;          // MFMA k-group

    const int bid = blockIdx.x;
    const int qt  = bid & (Tq / QBLK - 1);   // 32 q-tiles per (b,h)
    const int bh  = bid >> 5;
    const int b   = bh >> 4;
    const int h   = bh & (Hq - 1);

    // ---- Q fragment (A operand), pre-scaled by 1/sqrt(D)=0.125 (exact) ----
    const int qrow = qt * QBLK + wid * 16 + c;
    const float* qp = q + (((size_t)b * Tq + qrow) * Hq + h) * Dq;
    bf16x8 aq[2];
#pragma unroll
    for (int kk = 0; kk < 2; ++kk) {
        const float* p0 = qp + kk * 32 + g * 8;
        float4 f0 = *(const float4*)p0;
        float4 f1 = *(const float4*)(p0 + 4);
        bf16x8 a;
        a[0] = f2bf(f0.x * 0.125f); a[1] = f2bf(f0.y * 0.125f);
        a[2] = f2bf(f0.z * 0.125f); a[3] = f2bf(f0.w * 0.125f);
        a[4] = f2bf(f1.x * 0.125f); a[5] = f2bf(f1.y * 0.125f);
        a[6] = f2bf(f1.z * 0.125f); a[7] = f2bf(f1.w * 0.125f);
        aq[kk] = a;
    }

    float m_r[4], l_r[4];
    f32x4 oacc[4];
#pragma unroll
    for (int r = 0; r < 4; ++r) { m_r[r] = -1e30f; l_r[r] = 0.f; }
#pragma unroll
    for (int dt = 0; dt < 4; ++dt) oacc[dt] = (f32x4){0.f, 0.f, 0.f, 0.f};

    const int sr  = tid >> 2;            // staging kv-row 0..63
    const int sq4 = tid & 3;
    const int sd0 = sq4 * 16;            // staging d base

    for (int s0 = 0; s0 < Sq; s0 += KVBLK) {
        __syncthreads();   // previous iteration's LDS reads complete
        // ---- stage K (row-major) and V (transposed) as bf16 ----
        {
            const float* kp = kv + ((((size_t)b * Sq + s0 + sr) * 2 + 0) * Hq + h) * Dq + sd0;
            const float* vp = kp + (size_t)Hq * Dq;   // [s][1][h][d]
            float4 k0 = *(const float4*)(kp + 0);
            float4 k1 = *(const float4*)(kp + 4);
            float4 k2 = *(const float4*)(kp + 8);
            float4 k3 = *(const float4*)(kp + 12);
            bf16x8 w0, w1;
            w0[0]=f2bf(k0.x); w0[1]=f2bf(k0.y); w0[2]=f2bf(k0.z); w0[3]=f2bf(k0.w);
            w0[4]=f2bf(k1.x); w0[5]=f2bf(k1.y); w0[6]=f2bf(k1.z); w0[7]=f2bf(k1.w);
            w1[0]=f2bf(k2.x); w1[1]=f2bf(k2.y); w1[2]=f2bf(k2.z); w1[3]=f2bf(k2.w);
            w1[4]=f2bf(k3.x); w1[5]=f2bf(k3.y); w1[6]=f2bf(k3.z); w1[7]=f2bf(k3.w);
            const int swz = (sr & 7) << 4;
            *(bf16x8*)((char*)Kl + sr * 128 + ((sd0 * 2)      ^ swz)) = w0;
            *(bf16x8*)((char*)Kl + sr * 128 + ((sd0 * 2 + 16) ^ swz)) = w1;
#pragma unroll
            for (int ii = 0; ii < 4; ++ii) {
                float4 vv = *(const float4*)(vp + 4 * ii);
                const int db = sd0 + 4 * ii;
                float vals[4] = {vv.x, vv.y, vv.z, vv.w};
#pragma unroll
                for (int jj = 0; jj < 4; ++jj) {
                    const int d = db + jj;
                    const int off = d * 128 + ((sr * 2) ^ (((d ^ (d >> 4)) & 7) << 4));
                    *(short*)((char*)Vt + off) = f2bf(vals[jj]);
                }
            }
        }
        __syncthreads();

        // ---- QK^T: S[16 x 64] per wave ----
        f32x4 sac[4];
#pragma unroll
        for (int ks = 0; ks < 4; ++ks) {
            const int row = ks * 16 + c;
            const int swz = (row & 7) << 4;
            bf16x8 bk0 = *(const bf16x8*)((const char*)Kl + row * 128 + ((g * 16)      ^ swz));
            bf16x8 bk1 = *(const bf16x8*)((const char*)Kl + row * 128 + ((64 + g * 16) ^ swz));
            f32x4 z = {0.f, 0.f, 0.f, 0.f};
            z = __builtin_amdgcn_mfma_f32_16x16x32_bf16(aq[0], bk0, z, 0, 0, 0);
            z = __builtin_amdgcn_mfma_f32_16x16x32_bf16(aq[1], bk1, z, 0, 0, 0);
            sac[ks] = z;
        }

        // ---- online softmax (row = 4g+r, cols across 16 lanes of group g) ----
        float pr[4][4];
#pragma unroll
        for (int r = 0; r < 4; ++r) {
            float v = fmaxf(fmaxf(sac[0][r], sac[1][r]), fmaxf(sac[2][r], sac[3][r]));
            v = fmaxf(v, __shfl_xor(v, 1, 64));
            v = fmaxf(v, __shfl_xor(v, 2, 64));
            v = fmaxf(v, __shfl_xor(v, 4, 64));
            v = fmaxf(v, __shfl_xor(v, 8, 64));
            const float mnew  = fmaxf(m_r[r], v);
            const float alpha = __expf(m_r[r] - mnew);
            m_r[r] = mnew;
            float s = 0.f;
#pragma unroll
            for (int ks = 0; ks < 4; ++ks) {
                const float p = __expf(sac[ks][r] - mnew);
                pr[ks][r] = p;
                s += p;
            }
            s += __shfl_xor(s, 1, 64);
            s += __shfl_xor(s, 2, 64);
            s += __shfl_xor(s, 4, 64);
            s += __shfl_xor(s, 8, 64);
            l_r[r] = l_r[r] * alpha + s;
#pragma unroll
            for (int dt = 0; dt < 4; ++dt) oacc[dt][r] *= alpha;
        }

        // ---- P (bf16) -> per-wave LDS (C-layout -> A-layout fixup) ----
        {
            char* pw = (char*)&Pl[wid][0];
#pragma unroll
            for (int ks = 0; ks < 4; ++ks)
#pragma unroll
                for (int r = 0; r < 4; ++r) {
                    const int row = 4 * g + r;
                    const int col = ks * 16 + c;
                    *(short*)(pw + row * 128 + ((col * 2) ^ ((row & 7) << 4))) = f2bf(pr[ks][r]);
                }
        }

        // ---- PV: O[16 x 64] += P[16 x 64] * V[64 x 64] ----
        {
            const char* pw = (const char*)&Pl[wid][0];
            const int pswz = (c & 7) << 4;
#pragma unroll
            for (int kc = 0; kc < 2; ++kc) {
                bf16x8 ap = *(const bf16x8*)(pw + c * 128 + ((kc * 64 + g * 16) ^ pswz));
#pragma unroll
                for (int dt = 0; dt < 4; ++dt) {
                    const int d = dt * 16 + c;
                    const int vswz = ((d ^ (d >> 4)) & 7) << 4;
                    bf16x8 bv = *(const bf16x8*)((const char*)Vt + d * 128 +
                                                 ((kc * 64 + g * 16) ^ vswz));
                    oacc[dt] = __builtin_amdgcn_mfma_f32_16x16x32_bf16(ap, bv, oacc[dt], 0, 0, 0);
                }
            }
        }
    }

    // ---- epilogue: normalize by l and store fp32 ----
    float inv[4];
#pragma unroll
    for (int r = 0; r < 4; ++r) inv[r] = 1.f / l_r[r];
    float* op = out + (((size_t)b * Tq + qt * QBLK + wid * 16) * Hq + h) * Dq;
#pragma unroll
    for (int dt = 0; dt < 4; ++dt)
#pragma unroll
        for (int r = 0; r < 4; ++r) {
            const int row = 4 * g + r;
            op[(size_t)row * (Hq * Dq) + dt * 16 + c] = oacc[dt][r] * inv[r];
        }
}

extern "C" void kernel_launch(void* const* d_in, const int* in_sizes, int n_in,
                              void* d_out, int out_size, void* d_ws, size_t ws_size,
                              hipStream_t stream) {
    const float* q  = (const float*)d_in[0];
    const float* kv = (const float*)d_in[1];
    float* out = (float*)d_out;
    dim3 grid(Bq * Hq * (Tq / QBLK));   // 2048 blocks
    dim3 block(256);
    fattn_fwd<<<grid, block, 0, stream>>>(q, kv, out);
}

// Round 2
// 216.122 us; speedup vs baseline: 1.4554x; 1.4554x over previous
//
#include <hip/hip_runtime.h>
#include <hip/hip_bf16.h>

#define Bq 4
#define Tq 2048
#define Sq 2048
#define Hq 16
#define Dq 64
#define KVBLK 64
#define NT (Sq / KVBLK)

typedef short bf16x8 __attribute__((ext_vector_type(8)));
typedef float f32x4 __attribute__((ext_vector_type(4)));
typedef int   i32x4 __attribute__((ext_vector_type(4)));
typedef int   i32x2 __attribute__((ext_vector_type(2)));
typedef unsigned int u32;

static __device__ __forceinline__ u32 pk2(float a, float b) {
    // pack two floats into a bf16 pair (RNE), low short = a
    u32 ua = __float_as_uint(a); ua += 0x7fffu + ((ua >> 16) & 1u);
    u32 ub = __float_as_uint(b); ub += 0x7fffu + ((ub >> 16) & 1u);
    return (ua >> 16) | (ub & 0xffff0000u);
}

__global__ __launch_bounds__(256, 4) void fattn_fwd(
    const float* __restrict__ q, const float* __restrict__ kvp,
    float* __restrict__ out)
{
    __shared__ __align__(16) short Kl[2][KVBLK * 64];   // [kv][d] bf16, swizzled
    __shared__ __align__(16) short Vt[2][64 * KVBLK];   // [d][kv] bf16, swizzled

    const int tid  = threadIdx.x;
    const int lane = tid & 63;
    const int wid  = tid >> 6;
    const int c    = lane & 15;          // q index within wave tile
    const int g    = lane >> 4;          // k-group

    // XCD-aware swizzle: 2048 blocks = 8 XCDs x 256; keep (b,h) panels on one XCD
    const int lbid = ((blockIdx.x & 7) << 8) | (blockIdx.x >> 3);
    const int qt = lbid & 31;
    const int bh = lbid >> 5;
    const int b  = bh >> 4;
    const int h  = bh & 15;

    // scale 1/sqrt(64) * log2(e): softmax done in base 2
    const float QSCL = 0.125f * 1.4426950408889634f;

    // ---- Q fragments (B-operand of swapped QK^T): Q[q=c][d=32kc+8g+j] ----
    const int qrow = (qt << 6) + (wid << 4) + c;
    const float* qp = q + (((size_t)b * Tq + qrow) * Hq + h) * Dq;
    bf16x8 aq[2];
#pragma unroll
    for (int kc = 0; kc < 2; ++kc) {
        f32x4 f0 = *(const f32x4*)(qp + kc * 32 + g * 8);
        f32x4 f1 = *(const f32x4*)(qp + kc * 32 + g * 8 + 4);
        i32x4 w;
        w[0] = (int)pk2(f0[0] * QSCL, f0[1] * QSCL);
        w[1] = (int)pk2(f0[2] * QSCL, f0[3] * QSCL);
        w[2] = (int)pk2(f1[0] * QSCL, f1[1] * QSCL);
        w[3] = (int)pk2(f1[2] * QSCL, f1[3] * QSCL);
        aq[kc] = __builtin_bit_cast(bf16x8, w);
    }

    // staging assignments
    const int ksr = tid >> 2;            // K: kv row 0..63
    const int ksd = (tid & 3) << 4;      // K: d base {0,16,32,48}
    const int vw4 = tid >> 4;            // V: kv block (4 rows) 0..15
    const int vd0 = (tid & 15) << 2;     // V: d base {0,4,...,60}

    const float* kbase = kvp + (size_t)b * Sq * 2 * Hq * Dq + h * Dq;
    // K(s,d) = kbase + s*2048 + d ;  V(s,d) = kbase + s*2048 + 1024 + d

    f32x4 kr0, kr1, kr2, kr3, vr0, vr1, vr2, vr3;

    auto ISSUE = [&](int t) {
        const float* kp = kbase + (size_t)(t * KVBLK + ksr) * 2048 + ksd;
        kr0 = *(const f32x4*)(kp);
        kr1 = *(const f32x4*)(kp + 4);
        kr2 = *(const f32x4*)(kp + 8);
        kr3 = *(const f32x4*)(kp + 12);
        const float* vp = kbase + (size_t)(t * KVBLK + (vw4 << 2)) * 2048 + 1024 + vd0;
        vr0 = *(const f32x4*)(vp);
        vr1 = *(const f32x4*)(vp + 2048);
        vr2 = *(const f32x4*)(vp + 4096);
        vr3 = *(const f32x4*)(vp + 6144);
    };

    auto WRITE = [&](int t) {
        const int bp = t & 1;
        char* Kb = (char*)Kl[bp];
        char* Vb = (char*)Vt[bp];
        const int kswz = (ksr & 7) << 4;
        i32x4 w;
        w[0] = (int)pk2(kr0[0], kr0[1]); w[1] = (int)pk2(kr0[2], kr0[3]);
        w[2] = (int)pk2(kr1[0], kr1[1]); w[3] = (int)pk2(kr1[2], kr1[3]);
        *(bf16x8*)(Kb + ksr * 128 + (((ksd << 1)     ) ^ kswz)) = __builtin_bit_cast(bf16x8, w);
        w[0] = (int)pk2(kr2[0], kr2[1]); w[1] = (int)pk2(kr2[2], kr2[3]);
        w[2] = (int)pk2(kr3[0], kr3[1]); w[3] = (int)pk2(kr3[2], kr3[3]);
        *(bf16x8*)(Kb + ksr * 128 + (((ksd << 1) + 16) ^ kswz)) = __builtin_bit_cast(bf16x8, w);
#pragma unroll
        for (int j = 0; j < 4; ++j) {    // 4x4 register transpose of V block
            i32x2 t2;
            t2[0] = (int)pk2(vr0[j], vr1[j]);
            t2[1] = (int)pk2(vr2[j], vr3[j]);
            const int row = vd0 + j;
            *(i32x2*)(Vb + row * 128 + ((vw4 << 3) ^ ((row & 7) << 4))) = t2;
        }
    };

    ISSUE(0);
    WRITE(0);
    ISSUE(1);

    float m_r = -1e30f, l_r = 0.f;
    f32x4 oacc[4];
#pragma unroll
    for (int dt = 0; dt < 4; ++dt) oacc[dt] = (f32x4){0.f, 0.f, 0.f, 0.f};

    const int cswz = (c & 7) << 4;
    const int src0 = (((g << 1)    ) & 3) * 16 + c;
    const int src1 = (((g << 1) | 1) & 3) * 16 + c;
    const bool ghi = (g >= 2);

    for (int t = 0; t < NT; ++t) {
        __syncthreads();                       // buf[t&1] ready for all waves
        const int bp = t & 1;
        const char* Kb = (const char*)Kl[bp];
        const char* Vb = (const char*)Vt[bp];

        // ---- QK^T swapped: sac[ks] = S^T[kv=16ks+4g+r][q=c] ----
        f32x4 sac[4];
#pragma unroll
        for (int ks = 0; ks < 4; ++ks) {
            const char* rb = Kb + ((ks << 4) + c) * 128;
            bf16x8 kf0 = *(const bf16x8*)(rb + (((g << 4)     ) ^ cswz));
            bf16x8 kf1 = *(const bf16x8*)(rb + ((64 + (g << 4)) ^ cswz));
            f32x4 z = (f32x4){0.f, 0.f, 0.f, 0.f};
            z = __builtin_amdgcn_mfma_f32_16x16x32_bf16(kf0, aq[0], z, 0, 0, 0);
            z = __builtin_amdgcn_mfma_f32_16x16x32_bf16(kf1, aq[1], z, 0, 0, 0);
            sac[ks] = z;
        }

        // ---- online softmax (base 2), one q per lane, 4 shfl total ----
        float vmax = -1e30f;
#pragma unroll
        for (int ks = 0; ks < 4; ++ks)
#pragma unroll
            for (int r = 0; r < 4; ++r) vmax = fmaxf(vmax, sac[ks][r]);
        vmax = fmaxf(vmax, __shfl_xor(vmax, 16, 64));
        vmax = fmaxf(vmax, __shfl_xor(vmax, 32, 64));
        const float mnew  = fmaxf(m_r, vmax);
        const float alpha = exp2f(m_r - mnew);
        m_r = mnew;
        float ssum = 0.f;
#pragma unroll
        for (int ks = 0; ks < 4; ++ks)
#pragma unroll
            for (int r = 0; r < 4; ++r) {
                const float p = exp2f(sac[ks][r] - mnew);
                sac[ks][r] = p;
                ssum += p;
            }
        ssum += __shfl_xor(ssum, 16, 64);
        ssum += __shfl_xor(ssum, 32, 64);
        l_r = l_r * alpha + ssum;
#pragma unroll
        for (int dt = 0; dt < 4; ++dt) oacc[dt] *= alpha;

        // ---- pack P to bf16 pairs: pw_[ks][h] = {r=2h, r=2h+1} ----
        u32 pw_[4][2];
#pragma unroll
        for (int ks = 0; ks < 4; ++ks) {
            pw_[ks][0] = pk2(sac[ks][0], sac[ks][1]);
            pw_[ks][1] = pk2(sac[ks][2], sac[ks][3]);
        }

        // ---- P redistribution (C-layout -> B-frag) + PV ----
        // B-frag elem j=4t+r: kv=32kc+8g+j held at lane g'=(2g+t)&3, ks'=2kc+(g>>1)
#pragma unroll
        for (int kc = 0; kc < 2; ++kc) {
            const int kA = kc << 1, kB = kA | 1;
            const u32 a0 = (u32)__shfl((int)pw_[kA][0], src0, 64);
            const u32 a1 = (u32)__shfl((int)pw_[kA][1], src0, 64);
            const u32 a2 = (u32)__shfl((int)pw_[kA][0], src1, 64);
            const u32 a3 = (u32)__shfl((int)pw_[kA][1], src1, 64);
            const u32 b0 = (u32)__shfl((int)pw_[kB][0], src0, 64);
            const u32 b1 = (u32)__shfl((int)pw_[kB][1], src0, 64);
            const u32 b2 = (u32)__shfl((int)pw_[kB][0], src1, 64);
            const u32 b3 = (u32)__shfl((int)pw_[kB][1], src1, 64);
            i32x4 w;
            w[0] = (int)(ghi ? b0 : a0);
            w[1] = (int)(ghi ? b1 : a1);
            w[2] = (int)(ghi ? b2 : a2);
            w[3] = (int)(ghi ? b3 : a3);
            const bf16x8 pf = __builtin_bit_cast(bf16x8, w);
#pragma unroll
            for (int dt = 0; dt < 4; ++dt) {
                const bf16x8 vf = *(const bf16x8*)(Vb + ((dt << 4) + c) * 128 +
                                                   (((kc << 6) + (g << 4)) ^ cswz));
                oacc[dt] = __builtin_amdgcn_mfma_f32_16x16x32_bf16(vf, pf, oacc[dt], 0, 0, 0);
            }
        }

        // ---- T14: convert+write next tile late, issue tile t+2 early ----
        if (t + 1 < NT) WRITE(t + 1);
        if (t + 2 < NT) ISSUE(t + 2);
    }

    // ---- epilogue: O^T[d=16dt+4g+r][q=c] -> out[q][d], float4 stores ----
    const float inv = 1.0f / l_r;
    float* op = out + (((size_t)b * Tq + qrow) * Hq + h) * Dq;
#pragma unroll
    for (int dt = 0; dt < 4; ++dt) {
        f32x4 o = oacc[dt] * inv;
        *(f32x4*)(op + (dt << 4) + (g << 2)) = o;
    }
}

extern "C" void kernel_launch(void* const* d_in, const int* in_sizes, int n_in,
                              void* d_out, int out_size, void* d_ws, size_t ws_size,
                              hipStream_t stream) {
    const float* q  = (const float*)d_in[0];
    const float* kv = (const float*)d_in[1];
    float* out = (float*)d_out;
    dim3 grid(Bq * Hq * (Tq / KVBLK));   // 2048 blocks (64 q-rows per block)
    dim3 block(256);
    fattn_fwd<<<grid, block, 0, stream>>>(q, kv, out);
}

// Round 4
// 205.000 us; speedup vs baseline: 1.5344x; 1.0543x over previous
//
#include <hip/hip_runtime.h>
#include <hip/hip_bf16.h>

#define Bq 4
#define Tq 2048
#define Sq 2048
#define Hq 16
#define Dq 64
#define KVBLK 64
#define NT (Sq / KVBLK)

typedef short bf16x8 __attribute__((ext_vector_type(8)));
typedef short bf16x4 __attribute__((ext_vector_type(4)));
typedef float f32x4 __attribute__((ext_vector_type(4)));
typedef int   i32x4 __attribute__((ext_vector_type(4)));
typedef int   i32x2 __attribute__((ext_vector_type(2)));
typedef unsigned int u32;

#if defined(__has_builtin)
#if __has_builtin(__builtin_amdgcn_mfma_f32_16x16x16bf16_1k)
#define USE_MFMA16 1
#endif
#endif
#ifndef USE_MFMA16
#define USE_MFMA16 0
#endif

static __device__ __forceinline__ u32 pkc(float a, float b) {
    // pack two floats into a bf16 pair (RNE), low short = a
    u32 ua = __float_as_uint(a); ua += 0x7fffu + ((ua >> 16) & 1u);
    u32 ub = __float_as_uint(b); ub += 0x7fffu + ((ub >> 16) & 1u);
    return (ua >> 16) | (ub & 0xffff0000u);
}

__global__ __launch_bounds__(256, 4) void fattn_fwd(
    const float* __restrict__ q, const float* __restrict__ kvp,
    float* __restrict__ out)
{
    __shared__ __align__(16) short Kl[2][KVBLK * 64];   // [kv][d] bf16, swizzled
    __shared__ __align__(16) short Vt[2][64 * KVBLK];   // [d][kv] bf16, swizzled

    const int tid = threadIdx.x;
    const int c   = tid & 15;            // q index within wave tile
    const int g   = (tid >> 4) & 3;      // k-group
    const int wid = tid >> 6;

    // XCD-aware swizzle (2048 blocks = 8 XCDs x 256)
    const int lbid = ((blockIdx.x & 7) << 8) | (blockIdx.x >> 3);
    const int qt = lbid & 31;
    const int bh = lbid >> 5;
    const int b  = bh >> 4;
    const int h  = bh & 15;

    const float QSCL = 0.125f * 1.4426950408889634f;   // 1/sqrt(D) * log2(e)

    // ---- Q fragments (B operand of swapped QK^T) ----
    const int qrow = (qt << 6) + (wid << 4) + c;
    const float* qp = q + (((size_t)b * Tq + qrow) * Hq + h) * Dq;
    bf16x8 aq[2];
#pragma unroll
    for (int kc = 0; kc < 2; ++kc) {
        f32x4 f0 = *(const f32x4*)(qp + kc * 32 + g * 8);
        f32x4 f1 = *(const f32x4*)(qp + kc * 32 + g * 8 + 4);
        i32x4 w;
        w[0] = (int)pkc(f0[0] * QSCL, f0[1] * QSCL);
        w[1] = (int)pkc(f0[2] * QSCL, f0[3] * QSCL);
        w[2] = (int)pkc(f1[0] * QSCL, f1[1] * QSCL);
        w[3] = (int)pkc(f1[2] * QSCL, f1[3] * QSCL);
        aq[kc] = __builtin_bit_cast(bf16x8, w);
    }

    // staging assignments
    const int ksr = tid >> 2;            // K: kv row 0..63
    const int ksd = (tid & 3) << 4;      // K: d base
    const int vw4 = tid >> 4;            // V: kv block (4 rows) 0..15
    const int vd0 = (tid & 15) << 2;     // V: d base

    const float* kbase = kvp + (size_t)b * Sq * 2 * Hq * Dq + h * Dq;

    f32x4 kr0, kr1, kr2, kr3, vr0, vr1, vr2, vr3;

    auto ISSUE = [&](int t) {
        const float* kp = kbase + (size_t)(t * KVBLK + ksr) * 2048 + ksd;
        kr0 = *(const f32x4*)(kp);
        kr1 = *(const f32x4*)(kp + 4);
        kr2 = *(const f32x4*)(kp + 8);
        kr3 = *(const f32x4*)(kp + 12);
        const float* vp = kbase + (size_t)(t * KVBLK + (vw4 << 2)) * 2048 + 1024 + vd0;
        vr0 = *(const f32x4*)(vp);
        vr1 = *(const f32x4*)(vp + 2048);
        vr2 = *(const f32x4*)(vp + 4096);
        vr3 = *(const f32x4*)(vp + 6144);
    };

    auto WRITE = [&](int t) {
        const int bp = t & 1;
        char* Kb = (char*)Kl[bp];
        char* Vb = (char*)Vt[bp];
        const int kswz = (ksr & 7) << 4;
        i32x4 w;
        w[0] = (int)pkc(kr0[0], kr0[1]); w[1] = (int)pkc(kr0[2], kr0[3]);
        w[2] = (int)pkc(kr1[0], kr1[1]); w[3] = (int)pkc(kr1[2], kr1[3]);
        *(bf16x8*)(Kb + ksr * 128 + (((ksd << 1)     ) ^ kswz)) = __builtin_bit_cast(bf16x8, w);
        w[0] = (int)pkc(kr2[0], kr2[1]); w[1] = (int)pkc(kr2[2], kr2[3]);
        w[2] = (int)pkc(kr3[0], kr3[1]); w[3] = (int)pkc(kr3[2], kr3[3]);
        *(bf16x8*)(Kb + ksr * 128 + (((ksd << 1) + 16) ^ kswz)) = __builtin_bit_cast(bf16x8, w);
#pragma unroll
        for (int j = 0; j < 4; ++j) {    // 4x4 register transpose of V block
            i32x2 t2;
            t2[0] = (int)pkc(vr0[j], vr1[j]);
            t2[1] = (int)pkc(vr2[j], vr3[j]);
            const int row = vd0 + j;
            *(i32x2*)(Vb + row * 128 + ((vw4 << 3) ^ ((row & 7) << 4))) = t2;
        }
    };

    ISSUE(0);
    WRITE(0);

    float m_r = -1e30f, l_r = 0.f;
    f32x4 oacc[4];
#pragma unroll
    for (int dt = 0; dt < 4; ++dt) oacc[dt] = (f32x4){0.f, 0.f, 0.f, 0.f};

    const int cswz = (c & 7) << 4;
#if !USE_MFMA16
    const int src0 = (((g << 1)    ) & 3) * 16 + c;
    const int src1 = (((g << 1) | 1) & 3) * 16 + c;
    const bool ghi = (g >= 2);
#endif

    for (int t = 0; t < NT; ++t) {
        __syncthreads();                       // buf[t&1] ready for all waves
        const char* Kb = (const char*)Kl[t & 1];
        const char* Vb = (const char*)Vt[t & 1];

        // ---- QK^T swapped: sac[ks] = S^T[kv=16ks+4g+r][q=c] ----
        f32x4 sac[4];
        __builtin_amdgcn_s_setprio(1);
#pragma unroll
        for (int ks = 0; ks < 4; ++ks) {
            const char* rb = Kb + ((ks << 4) + c) * 128;
            bf16x8 kf0 = *(const bf16x8*)(rb + (((g << 4)     ) ^ cswz));
            bf16x8 kf1 = *(const bf16x8*)(rb + ((64 + (g << 4)) ^ cswz));
            f32x4 z = (f32x4){0.f, 0.f, 0.f, 0.f};
            z = __builtin_amdgcn_mfma_f32_16x16x32_bf16(kf0, aq[0], z, 0, 0, 0);
            z = __builtin_amdgcn_mfma_f32_16x16x32_bf16(kf1, aq[1], z, 0, 0, 0);
            sac[ks] = z;
        }
        __builtin_amdgcn_s_setprio(0);

        // T14: issue next tile's global loads early; latency hides under softmax+PV
        ISSUE(t + 1 < NT ? t + 1 : NT - 1);
        __builtin_amdgcn_sched_barrier(0);

        // ---- online softmax (base 2), one q per lane ----
        float vmax = sac[0][0];
#pragma unroll
        for (int ks = 0; ks < 4; ++ks)
#pragma unroll
            for (int r = 0; r < 4; ++r) vmax = fmaxf(vmax, sac[ks][r]);
        vmax = fmaxf(vmax, __shfl_xor(vmax, 16, 64));
        vmax = fmaxf(vmax, __shfl_xor(vmax, 32, 64));
        // T13 defer-max: only rescale when tile max grew materially (P <= 2^10)
        if (__any(vmax > m_r + 10.0f)) {
            const float mnew  = fmaxf(m_r, vmax);
            const float alpha = exp2f(m_r - mnew);
            m_r = mnew;
            l_r *= alpha;
#pragma unroll
            for (int dt = 0; dt < 4; ++dt) oacc[dt] *= alpha;
        }
        float ssum = 0.f;
#pragma unroll
        for (int ks = 0; ks < 4; ++ks)
#pragma unroll
            for (int r = 0; r < 4; ++r) {
                const float p = exp2f(sac[ks][r] - m_r);
                sac[ks][r] = p;
                ssum += p;
            }
        ssum += __shfl_xor(ssum, 16, 64);
        ssum += __shfl_xor(ssum, 32, 64);
        l_r += ssum;

#if USE_MFMA16
        // ---- P pack: C-layout rows kv=16ks+4g+r ARE the 16x16x16 B-frag slots ----
        u32 pw0[4], pw1[4];
#pragma unroll
        for (int ks = 0; ks < 4; ++ks) {
            pw0[ks] = pkc(sac[ks][0], sac[ks][1]);
            pw1[ks] = pkc(sac[ks][2], sac[ks][3]);
        }
        // ---- PV: O^T += V^T * P^T, 16 x mfma 16x16x16, zero cross-lane moves ----
        __builtin_amdgcn_s_setprio(1);
#pragma unroll
        for (int ks = 0; ks < 4; ++ks) {
            i32x2 pp; pp[0] = (int)pw0[ks]; pp[1] = (int)pw1[ks];
            const bf16x4 pf = __builtin_bit_cast(bf16x4, pp);
#pragma unroll
            for (int dt = 0; dt < 4; ++dt) {
                const bf16x4 vf = *(const bf16x4*)(Vb + ((dt << 4) + c) * 128 +
                                    (((ks << 5) + (g << 3)) ^ cswz));
                oacc[dt] = __builtin_amdgcn_mfma_f32_16x16x16bf16_1k(vf, pf, oacc[dt], 0, 0, 0);
            }
        }
        __builtin_amdgcn_s_setprio(0);
#else
        // fallback: shuffle-based P redistribution + 16x16x32 PV (round-2 path)
        u32 pw_[4][2];
#pragma unroll
        for (int ks = 0; ks < 4; ++ks) {
            pw_[ks][0] = pkc(sac[ks][0], sac[ks][1]);
            pw_[ks][1] = pkc(sac[ks][2], sac[ks][3]);
        }
#pragma unroll
        for (int kc = 0; kc < 2; ++kc) {
            const int kA = kc << 1, kB = kA | 1;
            const u32 a0 = (u32)__shfl((int)pw_[kA][0], src0, 64);
            const u32 a1 = (u32)__shfl((int)pw_[kA][1], src0, 64);
            const u32 a2 = (u32)__shfl((int)pw_[kA][0], src1, 64);
            const u32 a3 = (u32)__shfl((int)pw_[kA][1], src1, 64);
            const u32 b0 = (u32)__shfl((int)pw_[kB][0], src0, 64);
            const u32 b1 = (u32)__shfl((int)pw_[kB][1], src0, 64);
            const u32 b2 = (u32)__shfl((int)pw_[kB][0], src1, 64);
            const u32 b3 = (u32)__shfl((int)pw_[kB][1], src1, 64);
            i32x4 w;
            w[0] = (int)(ghi ? b0 : a0);
            w[1] = (int)(ghi ? b1 : a1);
            w[2] = (int)(ghi ? b2 : a2);
            w[3] = (int)(ghi ? b3 : a3);
            const bf16x8 pf = __builtin_bit_cast(bf16x8, w);
#pragma unroll
            for (int dt = 0; dt < 4; ++dt) {
                const bf16x8 vf = *(const bf16x8*)(Vb + ((dt << 4) + c) * 128 +
                                                   (((kc << 6) + (g << 4)) ^ cswz));
                oacc[dt] = __builtin_amdgcn_mfma_f32_16x16x32_bf16(vf, pf, oacc[dt], 0, 0, 0);
            }
        }
#endif

        // convert + write next tile into the other LDS buffer (consumed after
        // the barrier at the top of iteration t+1)
        WRITE(t + 1);
    }

    // ---- epilogue: O^T[d=16dt+4g+r][q=c] -> out[q][d] ----
    const float inv = 1.0f / l_r;
    float* op = out + (((size_t)b * Tq + qrow) * Hq + h) * Dq;
#pragma unroll
    for (int dt = 0; dt < 4; ++dt) {
        f32x4 o = oacc[dt] * inv;
        *(f32x4*)(op + (dt << 4) + (g << 2)) = o;
    }
}

extern "C" void kernel_launch(void* const* d_in, const int* in_sizes, int n_in,
                              void* d_out, int out_size, void* d_ws, size_t ws_size,
                              hipStream_t stream) {
    const float* q  = (const float*)d_in[0];
    const float* kv = (const float*)d_in[1];
    float* out = (float*)d_out;
    dim3 grid(Bq * Hq * (Tq / KVBLK));   // 2048 blocks (64 q-rows per block)
    dim3 block(256);
    fattn_fwd<<<grid, block, 0, stream>>>(q, kv, out);
}

// Round 6
// 166.334 us; speedup vs baseline: 1.8910x; 1.2325x over previous
//
#include <hip/hip_runtime.h>

#define Bq 4
#define Tq 2048
#define Sq 2048
#define Hq 16
#define Dq 64
#define KVBLK 64
#define NT (Sq / KVBLK)

typedef short bf16x8 __attribute__((ext_vector_type(8)));
typedef short bf16x4 __attribute__((ext_vector_type(4)));
typedef float f32x4 __attribute__((ext_vector_type(4)));
typedef int   i32x4 __attribute__((ext_vector_type(4)));
typedef int   i32x2 __attribute__((ext_vector_type(2)));
typedef unsigned int u32;

// The 16x16x16 bf16 MFMA builtin exists only in the DEVICE pass (round-4 run
// proved it's present and used on gfx950). Host pass gets a stub that is
// never executed — it just has to parse.
#if defined(__HIP_DEVICE_COMPILE__)
#if __has_builtin(__builtin_amdgcn_mfma_f32_16x16x16bf16_1k)
#define HAVE_MFMA16 1
#endif
#endif
#ifndef HAVE_MFMA16
#define HAVE_MFMA16 0
#endif

static __device__ __forceinline__ f32x4 pv_mfma16(bf16x4 vf, bf16x4 pf, f32x4 acc) {
#if HAVE_MFMA16
    return __builtin_amdgcn_mfma_f32_16x16x16bf16_1k(vf, pf, acc, 0, 0, 0);
#else
    return acc;   // host-pass stub only; device pass has the builtin
#endif
}

static __device__ __forceinline__ u32 pkc(float a, float b) {
    // pack two floats into a bf16 pair (RNE), low short = a
    u32 ua = __float_as_uint(a); ua += 0x7fffu + ((ua >> 16) & 1u);
    u32 ub = __float_as_uint(b); ub += 0x7fffu + ((ub >> 16) & 1u);
    return (ua >> 16) | (ub & 0xffff0000u);
}

static __device__ __forceinline__ void gload16(const void* g, void* l) {
    __builtin_amdgcn_global_load_lds(
        (const __attribute__((address_space(1))) u32*)g,
        (__attribute__((address_space(3))) u32*)l, 16, 0, 0);
}

// ---------------- pre-pass: kv fp32 -> bf16 LDS-tile images in ws ----------------
// wsK image per (b,h): 32 tiles x 8192B; tile = 64 rows(s) x 128B, byte
//   (s&63)*128 + ((d*2) ^ ((s&7)<<4))
// wsV image per (b,h): 32 tiles x 8192B; tile = 64 rows(d) x 128B, byte
//   d*128 + ((kv*2) ^ ((d&15)<<3))   [8B granules]
__global__ __launch_bounds__(256) void prepass(const float* __restrict__ kvp,
                                               char* __restrict__ wsK,
                                               char* __restrict__ wsV)
{
    if (blockIdx.x < 8192) {
        const int t = blockIdx.x * 256 + threadIdx.x;
        const int dq = t & 15, h = (t >> 4) & 15, s = (t >> 8) & 2047, b = t >> 19;
        const float* p = kvp + ((size_t)(b * 2048 + s)) * 2048 + h * 64 + dq * 4;
        const f32x4 f = *(const f32x4*)p;
        i32x2 w; w[0] = (int)pkc(f[0], f[1]); w[1] = (int)pkc(f[2], f[3]);
        char* d = wsK + (size_t)(b * 16 + h) * 262144 + (s >> 6) * 8192
                + (s & 63) * 128 + ((dq * 8) ^ ((s & 7) << 4));
        *(i32x2*)d = w;
    } else {
        const int t2 = (blockIdx.x - 8192) * 256 + threadIdx.x;
        const int dd = t2 & 63, h = (t2 >> 6) & 15, sq = (t2 >> 10) & 511, b = t2 >> 19;
        const float* p = kvp + ((size_t)(b * 2048 + sq * 4)) * 2048 + 1024 + h * 64 + dd;
        const float v0 = p[0], v1 = p[2048], v2 = p[4096], v3 = p[6144];
        i32x2 w; w[0] = (int)pkc(v0, v1); w[1] = (int)pkc(v2, v3);
        char* d = wsV + (size_t)(b * 16 + h) * 262144 + (sq >> 4) * 8192
                + dd * 128 + (((sq & 15) * 8) ^ ((dd & 15) << 3));
        *(i32x2*)d = w;
    }
}

// ---------------- main kernel: DMA-staged, conversion-free inner loop ----------------
__global__ __launch_bounds__(256, 4) void fattn_main(
    const float* __restrict__ q, const char* __restrict__ wsK,
    const char* __restrict__ wsV, float* __restrict__ out)
{
    __shared__ __align__(16) char Kl[2][8192];
    __shared__ __align__(16) char Vt[2][8192];

    const int tid = threadIdx.x;
    const int c   = tid & 15;
    const int g   = (tid >> 4) & 3;
    const int wid = tid >> 6;

    // XCD-aware swizzle (2048 blocks = 8 XCDs x 256)
    const int lbid = ((blockIdx.x & 7) << 8) | (blockIdx.x >> 3);
    const int qt = lbid & 31;
    const int bh = lbid >> 5;
    const int b  = bh >> 4;
    const int h  = bh & 15;

    const float QSCL = 0.125f * 1.4426950408889634f;   // 1/sqrt(D) * log2(e)

    // ---- Q fragments (B operand of swapped QK^T) ----
    const int qrow = (qt << 6) + (wid << 4) + c;
    const float* qp = q + (((size_t)b * Tq + qrow) * Hq + h) * Dq;
    bf16x8 aq[2];
#pragma unroll
    for (int kc = 0; kc < 2; ++kc) {
        f32x4 f0 = *(const f32x4*)(qp + kc * 32 + g * 8);
        f32x4 f1 = *(const f32x4*)(qp + kc * 32 + g * 8 + 4);
        i32x4 w;
        w[0] = (int)pkc(f0[0] * QSCL, f0[1] * QSCL);
        w[1] = (int)pkc(f0[2] * QSCL, f0[3] * QSCL);
        w[2] = (int)pkc(f1[0] * QSCL, f1[1] * QSCL);
        w[3] = (int)pkc(f1[2] * QSCL, f1[3] * QSCL);
        aq[kc] = __builtin_bit_cast(bf16x8, w);
    }

    const char* gK = wsK + (size_t)bh * 262144;
    const char* gV = wsV + (size_t)bh * 262144;
    const int go = tid * 16;           // per-lane global offset (= wave-base + lane*16)

    auto STAGE = [&](int t) {
        const int bp = (t & 1) * 8192;
        const char* gk = gK + t * 8192;
        const char* gv = gV + t * 8192;
        char* lk = &Kl[0][0] + bp + wid * 1024;   // wave-uniform LDS base
        char* lv = &Vt[0][0] + bp + wid * 1024;
        gload16(gk + go, lk);
        gload16(gk + 4096 + go, lk + 4096);
        gload16(gv + go, lv);
        gload16(gv + 4096 + go, lv + 4096);
    };

    STAGE(0);

    float m_r = -1e30f, l_r = 0.f;
    f32x4 oacc[4];
#pragma unroll
    for (int dt = 0; dt < 4; ++dt) oacc[dt] = (f32x4){0.f, 0.f, 0.f, 0.f};

    const int cswz = (c & 7) << 4;

    for (int t = 0; t < NT; ++t) {
        __syncthreads();               // drains this wave's DMA (vmcnt) + syncs block
        if (t + 1 < NT) STAGE(t + 1);  // DMA for next tile flies under this tile's compute
        const char* Kb = &Kl[0][0] + (t & 1) * 8192;
        const char* Vb = &Vt[0][0] + (t & 1) * 8192;

        // ---- QK^T swapped: sac[ks] = S^T[kv=16ks+4g+r][q=c] ----
        f32x4 sac[4];
        __builtin_amdgcn_s_setprio(1);
#pragma unroll
        for (int ks = 0; ks < 4; ++ks) {
            const char* rb = Kb + ((ks << 4) + c) * 128;
            bf16x8 kf0 = *(const bf16x8*)(rb + (((g << 4)     ) ^ cswz));
            bf16x8 kf1 = *(const bf16x8*)(rb + ((64 + (g << 4)) ^ cswz));
            f32x4 z = (f32x4){0.f, 0.f, 0.f, 0.f};
            z = __builtin_amdgcn_mfma_f32_16x16x32_bf16(kf0, aq[0], z, 0, 0, 0);
            z = __builtin_amdgcn_mfma_f32_16x16x32_bf16(kf1, aq[1], z, 0, 0, 0);
            sac[ks] = z;
        }
        __builtin_amdgcn_s_setprio(0);

        // ---- online softmax (base 2), one q per lane ----
        float vmax = sac[0][0];
#pragma unroll
        for (int ks = 0; ks < 4; ++ks)
#pragma unroll
            for (int r = 0; r < 4; ++r) vmax = fmaxf(vmax, sac[ks][r]);
        vmax = fmaxf(vmax, __shfl_xor(vmax, 16, 64));
        vmax = fmaxf(vmax, __shfl_xor(vmax, 32, 64));
        // T13 defer-max: only rescale when tile max grew materially (P <= 2^10)
        if (__any(vmax > m_r + 10.0f)) {
            const float mnew  = fmaxf(m_r, vmax);
            const float alpha = exp2f(m_r - mnew);
            m_r = mnew;
            l_r *= alpha;
#pragma unroll
            for (int dt = 0; dt < 4; ++dt) oacc[dt] *= alpha;
        }
        float ssum = 0.f;
#pragma unroll
        for (int ks = 0; ks < 4; ++ks)
#pragma unroll
            for (int r = 0; r < 4; ++r) {
                const float p = exp2f(sac[ks][r] - m_r);
                sac[ks][r] = p;
                ssum += p;
            }
        ssum += __shfl_xor(ssum, 16, 64);
        ssum += __shfl_xor(ssum, 32, 64);
        l_r += ssum;

        // ---- PV: C-layout rows kv=16ks+4g+r ARE the 16x16x16 B-frag slots ----
        __builtin_amdgcn_s_setprio(1);
#pragma unroll
        for (int ks = 0; ks < 4; ++ks) {
            i32x2 pp;
            pp[0] = (int)pkc(sac[ks][0], sac[ks][1]);
            pp[1] = (int)pkc(sac[ks][2], sac[ks][3]);
            const bf16x4 pf = __builtin_bit_cast(bf16x4, pp);
#pragma unroll
            for (int dt = 0; dt < 4; ++dt) {
                const i32x2 vv = *(const i32x2*)(Vb + ((dt << 4) + c) * 128 +
                                   (((ks << 5) + (g << 3)) ^ (c << 3)));
                const bf16x4 vf = __builtin_bit_cast(bf16x4, vv);
                oacc[dt] = pv_mfma16(vf, pf, oacc[dt]);
            }
        }
        __builtin_amdgcn_s_setprio(0);
    }

    // ---- epilogue: O^T[d=16dt+4g+r][q=c] -> out[q][d] ----
    const float inv = 1.0f / l_r;
    float* op = out + (((size_t)b * Tq + qrow) * Hq + h) * Dq;
#pragma unroll
    for (int dt = 0; dt < 4; ++dt) {
        f32x4 o = oacc[dt] * inv;
        *(f32x4*)(op + (dt << 4) + (g << 2)) = o;
    }
}

// ---------------- fallback (round-4 kernel) if ws too small ----------------
__global__ __launch_bounds__(256, 4) void fattn_v4(
    const float* __restrict__ q, const float* __restrict__ kvp,
    float* __restrict__ out)
{
    __shared__ __align__(16) short Kl[2][KVBLK * 64];
    __shared__ __align__(16) short Vt[2][64 * KVBLK];

    const int tid = threadIdx.x;
    const int c   = tid & 15;
    const int g   = (tid >> 4) & 3;
    const int wid = tid >> 6;

    const int lbid = ((blockIdx.x & 7) << 8) | (blockIdx.x >> 3);
    const int qt = lbid & 31;
    const int bh = lbid >> 5;
    const int b  = bh >> 4;
    const int h  = bh & 15;

    const float QSCL = 0.125f * 1.4426950408889634f;

    const int qrow = (qt << 6) + (wid << 4) + c;
    const float* qp = q + (((size_t)b * Tq + qrow) * Hq + h) * Dq;
    bf16x8 aq[2];
#pragma unroll
    for (int kc = 0; kc < 2; ++kc) {
        f32x4 f0 = *(const f32x4*)(qp + kc * 32 + g * 8);
        f32x4 f1 = *(const f32x4*)(qp + kc * 32 + g * 8 + 4);
        i32x4 w;
        w[0] = (int)pkc(f0[0] * QSCL, f0[1] * QSCL);
        w[1] = (int)pkc(f0[2] * QSCL, f0[3] * QSCL);
        w[2] = (int)pkc(f1[0] * QSCL, f1[1] * QSCL);
        w[3] = (int)pkc(f1[2] * QSCL, f1[3] * QSCL);
        aq[kc] = __builtin_bit_cast(bf16x8, w);
    }

    const int ksr = tid >> 2;
    const int ksd = (tid & 3) << 4;
    const int vw4 = tid >> 4;
    const int vd0 = (tid & 15) << 2;

    const float* kbase = kvp + (size_t)b * Sq * 2 * Hq * Dq + h * Dq;
    f32x4 kr0, kr1, kr2, kr3, vr0, vr1, vr2, vr3;

    auto ISSUE = [&](int t) {
        const float* kp = kbase + (size_t)(t * KVBLK + ksr) * 2048 + ksd;
        kr0 = *(const f32x4*)(kp);
        kr1 = *(const f32x4*)(kp + 4);
        kr2 = *(const f32x4*)(kp + 8);
        kr3 = *(const f32x4*)(kp + 12);
        const float* vp = kbase + (size_t)(t * KVBLK + (vw4 << 2)) * 2048 + 1024 + vd0;
        vr0 = *(const f32x4*)(vp);
        vr1 = *(const f32x4*)(vp + 2048);
        vr2 = *(const f32x4*)(vp + 4096);
        vr3 = *(const f32x4*)(vp + 6144);
    };
    auto WRITE = [&](int t) {
        const int bp = t & 1;
        char* Kb = (char*)Kl[bp];
        char* Vb = (char*)Vt[bp];
        const int kswz = (ksr & 7) << 4;
        i32x4 w;
        w[0] = (int)pkc(kr0[0], kr0[1]); w[1] = (int)pkc(kr0[2], kr0[3]);
        w[2] = (int)pkc(kr1[0], kr1[1]); w[3] = (int)pkc(kr1[2], kr1[3]);
        *(bf16x8*)(Kb + ksr * 128 + (((ksd << 1)     ) ^ kswz)) = __builtin_bit_cast(bf16x8, w);
        w[0] = (int)pkc(kr2[0], kr2[1]); w[1] = (int)pkc(kr2[2], kr2[3]);
        w[2] = (int)pkc(kr3[0], kr3[1]); w[3] = (int)pkc(kr3[2], kr3[3]);
        *(bf16x8*)(Kb + ksr * 128 + (((ksd << 1) + 16) ^ kswz)) = __builtin_bit_cast(bf16x8, w);
#pragma unroll
        for (int j = 0; j < 4; ++j) {
            i32x2 t2;
            t2[0] = (int)pkc(vr0[j], vr1[j]);
            t2[1] = (int)pkc(vr2[j], vr3[j]);
            const int row = vd0 + j;
            *(i32x2*)(Vb + row * 128 + ((vw4 << 3) ^ ((row & 7) << 4))) = t2;
        }
    };

    ISSUE(0);
    WRITE(0);

    float m_r = -1e30f, l_r = 0.f;
    f32x4 oacc[4];
#pragma unroll
    for (int dt = 0; dt < 4; ++dt) oacc[dt] = (f32x4){0.f, 0.f, 0.f, 0.f};
    const int cswz = (c & 7) << 4;

    for (int t = 0; t < NT; ++t) {
        __syncthreads();
        const char* Kb = (const char*)Kl[t & 1];
        const char* Vb = (const char*)Vt[t & 1];

        f32x4 sac[4];
#pragma unroll
        for (int ks = 0; ks < 4; ++ks) {
            const char* rb = Kb + ((ks << 4) + c) * 128;
            bf16x8 kf0 = *(const bf16x8*)(rb + (((g << 4)     ) ^ cswz));
            bf16x8 kf1 = *(const bf16x8*)(rb + ((64 + (g << 4)) ^ cswz));
            f32x4 z = (f32x4){0.f, 0.f, 0.f, 0.f};
            z = __builtin_amdgcn_mfma_f32_16x16x32_bf16(kf0, aq[0], z, 0, 0, 0);
            z = __builtin_amdgcn_mfma_f32_16x16x32_bf16(kf1, aq[1], z, 0, 0, 0);
            sac[ks] = z;
        }
        ISSUE(t + 1 < NT ? t + 1 : NT - 1);

        float vmax = sac[0][0];
#pragma unroll
        for (int ks = 0; ks < 4; ++ks)
#pragma unroll
            for (int r = 0; r < 4; ++r) vmax = fmaxf(vmax, sac[ks][r]);
        vmax = fmaxf(vmax, __shfl_xor(vmax, 16, 64));
        vmax = fmaxf(vmax, __shfl_xor(vmax, 32, 64));
        if (__any(vmax > m_r + 10.0f)) {
            const float mnew  = fmaxf(m_r, vmax);
            const float alpha = exp2f(m_r - mnew);
            m_r = mnew;
            l_r *= alpha;
#pragma unroll
            for (int dt = 0; dt < 4; ++dt) oacc[dt] *= alpha;
        }
        float ssum = 0.f;
#pragma unroll
        for (int ks = 0; ks < 4; ++ks)
#pragma unroll
            for (int r = 0; r < 4; ++r) {
                const float p = exp2f(sac[ks][r] - m_r);
                sac[ks][r] = p;
                ssum += p;
            }
        ssum += __shfl_xor(ssum, 16, 64);
        ssum += __shfl_xor(ssum, 32, 64);
        l_r += ssum;

#pragma unroll
        for (int ks = 0; ks < 4; ++ks) {
            i32x2 pp;
            pp[0] = (int)pkc(sac[ks][0], sac[ks][1]);
            pp[1] = (int)pkc(sac[ks][2], sac[ks][3]);
            const bf16x4 pf = __builtin_bit_cast(bf16x4, pp);
#pragma unroll
            for (int dt = 0; dt < 4; ++dt) {
                const i32x2 vv = *(const i32x2*)(Vb + ((dt << 4) + c) * 128 +
                                   (((ks << 5) + (g << 3)) ^ cswz));
                const bf16x4 vf = __builtin_bit_cast(bf16x4, vv);
                oacc[dt] = pv_mfma16(vf, pf, oacc[dt]);
            }
        }
        WRITE(t + 1);
    }

    const float inv = 1.0f / l_r;
    float* op = out + (((size_t)b * Tq + qrow) * Hq + h) * Dq;
#pragma unroll
    for (int dt = 0; dt < 4; ++dt) {
        f32x4 o = oacc[dt] * inv;
        *(f32x4*)(op + (dt << 4) + (g << 2)) = o;
    }
}

extern "C" void kernel_launch(void* const* d_in, const int* in_sizes, int n_in,
                              void* d_out, int out_size, void* d_ws, size_t ws_size,
                              hipStream_t stream) {
    const float* q  = (const float*)d_in[0];
    const float* kv = (const float*)d_in[1];
    float* out = (float*)d_out;
    if (ws_size >= (size_t)33554432) {
        char* wsK = (char*)d_ws;
        char* wsV = wsK + 16777216;
        prepass<<<dim3(16384), dim3(256), 0, stream>>>(kv, wsK, wsV);
        fattn_main<<<dim3(2048), dim3(256), 0, stream>>>(q, wsK, wsV, out);
    } else {
        fattn_v4<<<dim3(2048), dim3(256), 0, stream>>>(q, kv, out);
    }
}

// Round 8
// 139.606 us; speedup vs baseline: 2.2531x; 1.1915x over previous
//
#include <hip/hip_runtime.h>

#define Bq 4
#define Tq 2048
#define Sq 2048
#define Hq 16
#define Dq 64
#define KVBLK 64
#define NT (Sq / KVBLK)

typedef short bf16x8 __attribute__((ext_vector_type(8)));
typedef short bf16x4 __attribute__((ext_vector_type(4)));
typedef float f32x4 __attribute__((ext_vector_type(4)));
typedef int   i32x4 __attribute__((ext_vector_type(4)));
typedef int   i32x2 __attribute__((ext_vector_type(2)));
typedef unsigned int u32;

// Device-pass-only builtins (host pass gets parse-only stubs).
#if defined(__HIP_DEVICE_COMPILE__)
#if __has_builtin(__builtin_amdgcn_mfma_f32_16x16x16bf16_1k)
#define HAVE_MFMA16 1
#endif
#if __has_builtin(__builtin_amdgcn_exp2f)
#define HAVE_EXP2 1
#endif
#endif
#ifndef HAVE_MFMA16
#define HAVE_MFMA16 0
#endif
#ifndef HAVE_EXP2
#define HAVE_EXP2 0
#endif

static __device__ __forceinline__ f32x4 pv_mfma16(bf16x4 vf, bf16x4 pf, f32x4 acc) {
#if HAVE_MFMA16
    return __builtin_amdgcn_mfma_f32_16x16x16bf16_1k(vf, pf, acc, 0, 0, 0);
#else
    return acc;   // host-pass stub only
#endif
}

static __device__ __forceinline__ float fexp2(float x) {
#if HAVE_EXP2
    return __builtin_amdgcn_exp2f(x);   // raw v_exp_f32 (2^x), flushes large-neg to 0
#else
    return exp2f(x);
#endif
}

static __device__ __forceinline__ u32 pkc(float a, float b) {
    // integer RNE pack, low short = a  (PROVEN in rounds 1-6; r7's
    // v_cvt_pk_bf16_f32 asm produced wrong packing semantics -> absmax 0.18)
    u32 ua = __float_as_uint(a); ua += 0x7fffu + ((ua >> 16) & 1u);
    u32 ub = __float_as_uint(b); ub += 0x7fffu + ((ub >> 16) & 1u);
    return (ua >> 16) | (ub & 0xffff0000u);
}

static __device__ __forceinline__ void gload16(const void* g, void* l) {
    __builtin_amdgcn_global_load_lds(
        (const __attribute__((address_space(1))) u32*)g,
        (__attribute__((address_space(3))) u32*)l, 16, 0, 0);
}

// ---------------- pre-pass: kv fp32 -> bf16 LDS-tile images in ws ----------------
// wsK image per (b,h): 32 tiles x 8192B; tile = 64 rows(s) x 128B, byte
//   (s&63)*128 + ((d*2) ^ ((s&7)<<4))
// wsV image per (b,h): 32 tiles x 8192B; tile = 64 rows(d) x 128B, byte
//   d*128 + ((kv*2) ^ ((d&15)<<3))   [8B granules]
__global__ __launch_bounds__(256) void prepass(const float* __restrict__ kvp,
                                               char* __restrict__ wsK,
                                               char* __restrict__ wsV)
{
    if (blockIdx.x < 8192) {
        const int t = blockIdx.x * 256 + threadIdx.x;
        const int dq = t & 15, h = (t >> 4) & 15, s = (t >> 8) & 2047, b = t >> 19;
        const float* p = kvp + ((size_t)(b * 2048 + s)) * 2048 + h * 64 + dq * 4;
        const f32x4 f = *(const f32x4*)p;
        i32x2 w; w[0] = (int)pkc(f[0], f[1]); w[1] = (int)pkc(f[2], f[3]);
        char* d = wsK + (size_t)(b * 16 + h) * 262144 + (s >> 6) * 8192
                + (s & 63) * 128 + ((dq * 8) ^ ((s & 7) << 4));
        *(i32x2*)d = w;
    } else {
        const int t2 = (blockIdx.x - 8192) * 256 + threadIdx.x;
        const int dd = t2 & 63, h = (t2 >> 6) & 15, sq = (t2 >> 10) & 511, b = t2 >> 19;
        const float* p = kvp + ((size_t)(b * 2048 + sq * 4)) * 2048 + 1024 + h * 64 + dd;
        const float v0 = p[0], v1 = p[2048], v2 = p[4096], v3 = p[6144];
        i32x2 w; w[0] = (int)pkc(v0, v1); w[1] = (int)pkc(v2, v3);
        char* d = wsV + (size_t)(b * 16 + h) * 262144 + (sq >> 4) * 8192
                + dd * 128 + (((sq & 15) * 8) ^ ((dd & 15) << 3));
        *(i32x2*)d = w;
    }
}

// ---------------- main kernel: DMA-staged, low-VALU softmax ----------------
__global__ __launch_bounds__(256, 4) void fattn_main(
    const float* __restrict__ q, const char* __restrict__ wsK,
    const char* __restrict__ wsV, float* __restrict__ out)
{
    __shared__ __align__(16) char Kl[2][8192];
    __shared__ __align__(16) char Vt[2][8192];

    const int tid = threadIdx.x;
    const int c   = tid & 15;
    const int g   = (tid >> 4) & 3;
    const int wid = tid >> 6;

    // XCD-aware swizzle (2048 blocks = 8 XCDs x 256)
    const int lbid = ((blockIdx.x & 7) << 8) | (blockIdx.x >> 3);
    const int qt = lbid & 31;
    const int bh = lbid >> 5;
    const int b  = bh >> 4;
    const int h  = bh & 15;

    const float QSCL = 0.125f * 1.4426950408889634f;   // 1/sqrt(D) * log2(e)

    // ---- Q fragments (B operand of swapped QK^T) ----
    const int qrow = (qt << 6) + (wid << 4) + c;
    const float* qp = q + (((size_t)b * Tq + qrow) * Hq + h) * Dq;
    bf16x8 aq[2];
#pragma unroll
    for (int kc = 0; kc < 2; ++kc) {
        f32x4 f0 = *(const f32x4*)(qp + kc * 32 + g * 8);
        f32x4 f1 = *(const f32x4*)(qp + kc * 32 + g * 8 + 4);
        i32x4 w;
        w[0] = (int)pkc(f0[0] * QSCL, f0[1] * QSCL);
        w[1] = (int)pkc(f0[2] * QSCL, f0[3] * QSCL);
        w[2] = (int)pkc(f1[0] * QSCL, f1[1] * QSCL);
        w[3] = (int)pkc(f1[2] * QSCL, f1[3] * QSCL);
        aq[kc] = __builtin_bit_cast(bf16x8, w);
    }

    const char* gK = wsK + (size_t)bh * 262144;
    const char* gV = wsV + (size_t)bh * 262144;
    const int go = tid * 16;           // per-lane global offset (= wave-base + lane*16)

    auto STAGE = [&](int t) {
        const int bp = (t & 1) * 8192;
        const char* gk = gK + t * 8192;
        const char* gv = gV + t * 8192;
        char* lk = &Kl[0][0] + bp + wid * 1024;   // wave-uniform LDS base
        char* lv = &Vt[0][0] + bp + wid * 1024;
        gload16(gk + go, lk);
        gload16(gk + 4096 + go, lk + 4096);
        gload16(gv + go, lv);
        gload16(gv + 4096 + go, lv + 4096);
    };

    STAGE(0);

    float m_r = -1e30f;
    f32x4 lacc = (f32x4){0.f, 0.f, 0.f, 0.f};   // row-sum of P via ones-MFMA
    f32x4 oacc[4];
#pragma unroll
    for (int dt = 0; dt < 4; ++dt) oacc[dt] = (f32x4){0.f, 0.f, 0.f, 0.f};

    const int cswz = (c & 7) << 4;
    const bf16x4 vone = {(short)0x3F80, (short)0x3F80, (short)0x3F80, (short)0x3F80};

    for (int t = 0; t < NT; ++t) {
        __syncthreads();               // drains this wave's DMA (vmcnt) + syncs block
        if (t + 1 < NT) STAGE(t + 1);  // DMA for next tile flies under this tile's compute
        const char* Kb = &Kl[0][0] + (t & 1) * 8192;
        const char* Vb = &Vt[0][0] + (t & 1) * 8192;

        // ---- QK^T swapped: sac[ks] = S^T[kv=16ks+4g+r][q=c] ----
        f32x4 sac[4];
        __builtin_amdgcn_s_setprio(1);
#pragma unroll
        for (int ks = 0; ks < 4; ++ks) {
            const char* rb = Kb + ((ks << 4) + c) * 128;
            bf16x8 kf0 = *(const bf16x8*)(rb + (((g << 4)     ) ^ cswz));
            bf16x8 kf1 = *(const bf16x8*)(rb + ((64 + (g << 4)) ^ cswz));
            f32x4 z = (f32x4){0.f, 0.f, 0.f, 0.f};
            z = __builtin_amdgcn_mfma_f32_16x16x32_bf16(kf0, aq[0], z, 0, 0, 0);
            z = __builtin_amdgcn_mfma_f32_16x16x32_bf16(kf1, aq[1], z, 0, 0, 0);
            sac[ks] = z;
        }
        __builtin_amdgcn_s_setprio(0);

        // ---- per-lane max (tree, max3-fusable) ----
        float t0 = fmaxf(fmaxf(sac[0][0], sac[0][1]), fmaxf(sac[0][2], sac[0][3]));
        float t1 = fmaxf(fmaxf(sac[1][0], sac[1][1]), fmaxf(sac[1][2], sac[1][3]));
        float t2 = fmaxf(fmaxf(sac[2][0], sac[2][1]), fmaxf(sac[2][2], sac[2][3]));
        float t3 = fmaxf(fmaxf(sac[3][0], sac[3][1]), fmaxf(sac[3][2], sac[3][3]));
        const float ml = fmaxf(fmaxf(t0, t1), fmaxf(t2, t3));

        // T13 defer-max: full row-reduce + rescale only when max grew materially
        if (__any(ml > m_r + 10.0f)) {
            float vm = fmaxf(ml, __shfl_xor(ml, 16, 64));
            vm = fmaxf(vm, __shfl_xor(vm, 32, 64));
            const float mnew  = fmaxf(m_r, vm);
            const float alpha = fexp2(m_r - mnew);
            m_r = mnew;
            lacc *= alpha;
#pragma unroll
            for (int dt = 0; dt < 4; ++dt) oacc[dt] *= alpha;
        }

        // ---- P = 2^(s - m), P <= 2^10 ----
#pragma unroll
        for (int ks = 0; ks < 4; ++ks)
#pragma unroll
            for (int r = 0; r < 4; ++r)
                sac[ks][r] = fexp2(sac[ks][r] - m_r);

        // ---- pack + PV + l-sum via ones-MFMA ----
        // C-layout rows kv=16ks+4g+r ARE the 16x16x16 B-frag slots (k=4g+j)
        __builtin_amdgcn_s_setprio(1);
#pragma unroll
        for (int ks = 0; ks < 4; ++ks) {
            i32x2 pp;
            pp[0] = (int)pkc(sac[ks][0], sac[ks][1]);
            pp[1] = (int)pkc(sac[ks][2], sac[ks][3]);
            const bf16x4 pf = __builtin_bit_cast(bf16x4, pp);
            lacc = pv_mfma16(vone, pf, lacc);     // row-sum of P on the MFMA pipe
#pragma unroll
            for (int dt = 0; dt < 4; ++dt) {
                const i32x2 vv = *(const i32x2*)(Vb + ((dt << 4) + c) * 128 +
                                   (((ks << 5) + (g << 3)) ^ (c << 3)));
                const bf16x4 vf = __builtin_bit_cast(bf16x4, vv);
                oacc[dt] = pv_mfma16(vf, pf, oacc[dt]);
            }
        }
        __builtin_amdgcn_s_setprio(0);
    }

    // ---- epilogue: O^T[d=16dt+4g+r][q=c] / l -> out[q][d] ----
    const float inv = 1.0f / lacc[0];
    float* op = out + (((size_t)b * Tq + qrow) * Hq + h) * Dq;
#pragma unroll
    for (int dt = 0; dt < 4; ++dt) {
        f32x4 o = oacc[dt] * inv;
        *(f32x4*)(op + (dt << 4) + (g << 2)) = o;
    }
}

// ---------------- fallback (round-6 path) if ws too small ----------------
__global__ __launch_bounds__(256, 4) void fattn_v4(
    const float* __restrict__ q, const float* __restrict__ kvp,
    float* __restrict__ out)
{
    __shared__ __align__(16) short Kl[2][KVBLK * 64];
    __shared__ __align__(16) short Vt[2][64 * KVBLK];

    const int tid = threadIdx.x;
    const int c   = tid & 15;
    const int g   = (tid >> 4) & 3;
    const int wid = tid >> 6;

    const int lbid = ((blockIdx.x & 7) << 8) | (blockIdx.x >> 3);
    const int qt = lbid & 31;
    const int bh = lbid >> 5;
    const int b  = bh >> 4;
    const int h  = bh & 15;

    const float QSCL = 0.125f * 1.4426950408889634f;

    const int qrow = (qt << 6) + (wid << 4) + c;
    const float* qp = q + (((size_t)b * Tq + qrow) * Hq + h) * Dq;
    bf16x8 aq[2];
#pragma unroll
    for (int kc = 0; kc < 2; ++kc) {
        f32x4 f0 = *(const f32x4*)(qp + kc * 32 + g * 8);
        f32x4 f1 = *(const f32x4*)(qp + kc * 32 + g * 8 + 4);
        i32x4 w;
        w[0] = (int)pkc(f0[0] * QSCL, f0[1] * QSCL);
        w[1] = (int)pkc(f0[2] * QSCL, f0[3] * QSCL);
        w[2] = (int)pkc(f1[0] * QSCL, f1[1] * QSCL);
        w[3] = (int)pkc(f1[2] * QSCL, f1[3] * QSCL);
        aq[kc] = __builtin_bit_cast(bf16x8, w);
    }

    const int ksr = tid >> 2;
    const int ksd = (tid & 3) << 4;
    const int vw4 = tid >> 4;
    const int vd0 = (tid & 15) << 2;

    const float* kbase = kvp + (size_t)b * Sq * 2 * Hq * Dq + h * Dq;
    f32x4 kr0, kr1, kr2, kr3, vr0, vr1, vr2, vr3;

    auto ISSUE = [&](int t) {
        const float* kp = kbase + (size_t)(t * KVBLK + ksr) * 2048 + ksd;
        kr0 = *(const f32x4*)(kp);
        kr1 = *(const f32x4*)(kp + 4);
        kr2 = *(const f32x4*)(kp + 8);
        kr3 = *(const f32x4*)(kp + 12);
        const float* vp = kbase + (size_t)(t * KVBLK + (vw4 << 2)) * 2048 + 1024 + vd0;
        vr0 = *(const f32x4*)(vp);
        vr1 = *(const f32x4*)(vp + 2048);
        vr2 = *(const f32x4*)(vp + 4096);
        vr3 = *(const f32x4*)(vp + 6144);
    };
    auto WRITE = [&](int t) {
        const int bp = t & 1;
        char* Kb = (char*)Kl[bp];
        char* Vb = (char*)Vt[bp];
        const int kswz = (ksr & 7) << 4;
        i32x4 w;
        w[0] = (int)pkc(kr0[0], kr0[1]); w[1] = (int)pkc(kr0[2], kr0[3]);
        w[2] = (int)pkc(kr1[0], kr1[1]); w[3] = (int)pkc(kr1[2], kr1[3]);
        *(bf16x8*)(Kb + ksr * 128 + (((ksd << 1)     ) ^ kswz)) = __builtin_bit_cast(bf16x8, w);
        w[0] = (int)pkc(kr2[0], kr2[1]); w[1] = (int)pkc(kr2[2], kr2[3]);
        w[2] = (int)pkc(kr3[0], kr3[1]); w[3] = (int)pkc(kr3[2], kr3[3]);
        *(bf16x8*)(Kb + ksr * 128 + (((ksd << 1) + 16) ^ kswz)) = __builtin_bit_cast(bf16x8, w);
#pragma unroll
        for (int j = 0; j < 4; ++j) {
            i32x2 t2;
            t2[0] = (int)pkc(vr0[j], vr1[j]);
            t2[1] = (int)pkc(vr2[j], vr3[j]);
            const int row = vd0 + j;
            *(i32x2*)(Vb + row * 128 + ((vw4 << 3) ^ ((row & 7) << 4))) = t2;
        }
    };

    ISSUE(0);
    WRITE(0);

    float m_r = -1e30f, l_r = 0.f;
    f32x4 oacc[4];
#pragma unroll
    for (int dt = 0; dt < 4; ++dt) oacc[dt] = (f32x4){0.f, 0.f, 0.f, 0.f};
    const int cswz = (c & 7) << 4;

    for (int t = 0; t < NT; ++t) {
        __syncthreads();
        const char* Kb = (const char*)Kl[t & 1];
        const char* Vb = (const char*)Vt[t & 1];

        f32x4 sac[4];
#pragma unroll
        for (int ks = 0; ks < 4; ++ks) {
            const char* rb = Kb + ((ks << 4) + c) * 128;
            bf16x8 kf0 = *(const bf16x8*)(rb + (((g << 4)     ) ^ cswz));
            bf16x8 kf1 = *(const bf16x8*)(rb + ((64 + (g << 4)) ^ cswz));
            f32x4 z = (f32x4){0.f, 0.f, 0.f, 0.f};
            z = __builtin_amdgcn_mfma_f32_16x16x32_bf16(kf0, aq[0], z, 0, 0, 0);
            z = __builtin_amdgcn_mfma_f32_16x16x32_bf16(kf1, aq[1], z, 0, 0, 0);
            sac[ks] = z;
        }
        ISSUE(t + 1 < NT ? t + 1 : NT - 1);

        float vmax = sac[0][0];
#pragma unroll
        for (int ks = 0; ks < 4; ++ks)
#pragma unroll
            for (int r = 0; r < 4; ++r) vmax = fmaxf(vmax, sac[ks][r]);
        vmax = fmaxf(vmax, __shfl_xor(vmax, 16, 64));
        vmax = fmaxf(vmax, __shfl_xor(vmax, 32, 64));
        if (__any(vmax > m_r + 10.0f)) {
            const float mnew  = fmaxf(m_r, vmax);
            const float alpha = exp2f(m_r - mnew);
            m_r = mnew;
            l_r *= alpha;
#pragma unroll
            for (int dt = 0; dt < 4; ++dt) oacc[dt] *= alpha;
        }
        float ssum = 0.f;
#pragma unroll
        for (int ks = 0; ks < 4; ++ks)
#pragma unroll
            for (int r = 0; r < 4; ++r) {
                const float p = exp2f(sac[ks][r] - m_r);
                sac[ks][r] = p;
                ssum += p;
            }
        ssum += __shfl_xor(ssum, 16, 64);
        ssum += __shfl_xor(ssum, 32, 64);
        l_r += ssum;

#pragma unroll
        for (int ks = 0; ks < 4; ++ks) {
            i32x2 pp;
            pp[0] = (int)pkc(sac[ks][0], sac[ks][1]);
            pp[1] = (int)pkc(sac[ks][2], sac[ks][3]);
            const bf16x4 pf = __builtin_bit_cast(bf16x4, pp);
#pragma unroll
            for (int dt = 0; dt < 4; ++dt) {
                const i32x2 vv = *(const i32x2*)(Vb + ((dt << 4) + c) * 128 +
                                   (((ks << 5) + (g << 3)) ^ cswz));
                const bf16x4 vf = __builtin_bit_cast(bf16x4, vv);
                oacc[dt] = pv_mfma16(vf, pf, oacc[dt]);
            }
        }
        WRITE(t + 1);
    }

    const float inv = 1.0f / l_r;
    float* op = out + (((size_t)b * Tq + qrow) * Hq + h) * Dq;
#pragma unroll
    for (int dt = 0; dt < 4; ++dt) {
        f32x4 o = oacc[dt] * inv;
        *(f32x4*)(op + (dt << 4) + (g << 2)) = o;
    }
}

extern "C" void kernel_launch(void* const* d_in, const int* in_sizes, int n_in,
                              void* d_out, int out_size, void* d_ws, size_t ws_size,
                              hipStream_t stream) {
    const float* q  = (const float*)d_in[0];
    const float* kv = (const float*)d_in[1];
    float* out = (float*)d_out;
    if (ws_size >= (size_t)33554432) {
        char* wsK = (char*)d_ws;
        char* wsV = wsK + 16777216;
        prepass<<<dim3(16384), dim3(256), 0, stream>>>(kv, wsK, wsV);
        fattn_main<<<dim3(2048), dim3(256), 0, stream>>>(q, wsK, wsV, out);
    } else {
        fattn_v4<<<dim3(2048), dim3(256), 0, stream>>>(q, kv, out);
    }
}

// Round 9
// 126.513 us; speedup vs baseline: 2.4863x; 1.1035x over previous
//
#include <hip/hip_runtime.h>

#define Bq 4
#define Tq 2048
#define Sq 2048
#define Hq 16
#define Dq 64
#define KVBLK 64
#define NT (Sq / KVBLK)

typedef short bf16x8 __attribute__((ext_vector_type(8)));
typedef short bf16x4 __attribute__((ext_vector_type(4)));
typedef float f32x4 __attribute__((ext_vector_type(4)));
typedef int   i32x4 __attribute__((ext_vector_type(4)));
typedef int   i32x2 __attribute__((ext_vector_type(2)));
typedef unsigned int u32;

// Device-pass-only builtins (host pass gets parse-only stubs).
#if defined(__HIP_DEVICE_COMPILE__)
#if __has_builtin(__builtin_amdgcn_mfma_f32_16x16x16bf16_1k)
#define HAVE_MFMA16 1
#endif
#if __has_builtin(__builtin_amdgcn_exp2f)
#define HAVE_EXP2 1
#endif
#endif
#ifndef HAVE_MFMA16
#define HAVE_MFMA16 0
#endif
#ifndef HAVE_EXP2
#define HAVE_EXP2 0
#endif

static __device__ __forceinline__ f32x4 pv_mfma16(bf16x4 vf, bf16x4 pf, f32x4 acc) {
#if HAVE_MFMA16
    return __builtin_amdgcn_mfma_f32_16x16x16bf16_1k(vf, pf, acc, 0, 0, 0);
#else
    return acc;   // host-pass stub only
#endif
}

static __device__ __forceinline__ float fexp2(float x) {
#if HAVE_EXP2
    return __builtin_amdgcn_exp2f(x);   // raw v_exp_f32 (2^x)
#else
    return exp2f(x);
#endif
}

static __device__ __forceinline__ u32 pkc(float a, float b) {
    // integer RNE pack, low short = a (proven r1-r8; cvt_pk asm was r7's bug)
    u32 ua = __float_as_uint(a); ua += 0x7fffu + ((ua >> 16) & 1u);
    u32 ub = __float_as_uint(b); ub += 0x7fffu + ((ub >> 16) & 1u);
    return (ua >> 16) | (ub & 0xffff0000u);
}

static __device__ __forceinline__ void gload16(const void* g, void* l) {
    __builtin_amdgcn_global_load_lds(
        (const __attribute__((address_space(1))) u32*)g,
        (__attribute__((address_space(3))) u32*)l, 16, 0, 0);
}

// ---------------- pre-pass: kv fp32 -> bf16 LDS-tile images in ws ----------------
__global__ __launch_bounds__(256) void prepass(const float* __restrict__ kvp,
                                               char* __restrict__ wsK,
                                               char* __restrict__ wsV)
{
    if (blockIdx.x < 8192) {
        const int t = blockIdx.x * 256 + threadIdx.x;
        const int dq = t & 15, h = (t >> 4) & 15, s = (t >> 8) & 2047, b = t >> 19;
        const float* p = kvp + ((size_t)(b * 2048 + s)) * 2048 + h * 64 + dq * 4;
        const f32x4 f = *(const f32x4*)p;
        i32x2 w; w[0] = (int)pkc(f[0], f[1]); w[1] = (int)pkc(f[2], f[3]);
        char* d = wsK + (size_t)(b * 16 + h) * 262144 + (s >> 6) * 8192
                + (s & 63) * 128 + ((dq * 8) ^ ((s & 7) << 4));
        *(i32x2*)d = w;
    } else {
        const int t2 = (blockIdx.x - 8192) * 256 + threadIdx.x;
        const int dd = t2 & 63, h = (t2 >> 6) & 15, sq = (t2 >> 10) & 511, b = t2 >> 19;
        const float* p = kvp + ((size_t)(b * 2048 + sq * 4)) * 2048 + 1024 + h * 64 + dd;
        const float v0 = p[0], v1 = p[2048], v2 = p[4096], v3 = p[6144];
        i32x2 w; w[0] = (int)pkc(v0, v1); w[1] = (int)pkc(v2, v3);
        char* d = wsV + (size_t)(b * 16 + h) * 262144 + (sq >> 4) * 8192
                + dd * 128 + (((sq & 15) * 8) ^ ((dd & 15) << 3));
        *(i32x2*)d = w;
    }
}

// ---------------- main kernel: 32 q-rows/wave, K/V LDS reads amortized 2x ----------------
__global__ __launch_bounds__(256, 4) void fattn_main(
    const float* __restrict__ q, const char* __restrict__ wsK,
    const char* __restrict__ wsV, float* __restrict__ out)
{
    __shared__ __align__(16) char Kl[2][8192];
    __shared__ __align__(16) char Vt[2][8192];

    const int tid = threadIdx.x;
    const int c   = tid & 15;
    const int g   = (tid >> 4) & 3;
    const int wid = tid >> 6;

    // XCD-aware swizzle (1024 blocks = 8 XCDs x 128)
    const int lbid = ((blockIdx.x & 7) << 7) | (blockIdx.x >> 3);
    const int qt = lbid & 15;            // 16 q-tiles of 128 rows
    const int bh = lbid >> 4;
    const int b  = bh >> 4;
    const int h  = bh & 15;

    const float QSCL = 0.125f * 1.4426950408889634f;   // 1/sqrt(D) * log2(e)

    // ---- Two Q fragment sets: rows qrow (half0) and qrow+16 (half1) ----
    const int qrow = (qt << 7) + (wid << 5) + c;
    const float* qp0 = q + (((size_t)b * Tq + qrow) * Hq + h) * Dq;
    bf16x8 aq0[2], aq1[2];
#pragma unroll
    for (int kc = 0; kc < 2; ++kc) {
        {
            f32x4 f0 = *(const f32x4*)(qp0 + kc * 32 + g * 8);
            f32x4 f1 = *(const f32x4*)(qp0 + kc * 32 + g * 8 + 4);
            i32x4 w;
            w[0] = (int)pkc(f0[0] * QSCL, f0[1] * QSCL);
            w[1] = (int)pkc(f0[2] * QSCL, f0[3] * QSCL);
            w[2] = (int)pkc(f1[0] * QSCL, f1[1] * QSCL);
            w[3] = (int)pkc(f1[2] * QSCL, f1[3] * QSCL);
            aq0[kc] = __builtin_bit_cast(bf16x8, w);
        }
        {
            const float* qp1 = qp0 + 16 * Hq * Dq;
            f32x4 f0 = *(const f32x4*)(qp1 + kc * 32 + g * 8);
            f32x4 f1 = *(const f32x4*)(qp1 + kc * 32 + g * 8 + 4);
            i32x4 w;
            w[0] = (int)pkc(f0[0] * QSCL, f0[1] * QSCL);
            w[1] = (int)pkc(f0[2] * QSCL, f0[3] * QSCL);
            w[2] = (int)pkc(f1[0] * QSCL, f1[1] * QSCL);
            w[3] = (int)pkc(f1[2] * QSCL, f1[3] * QSCL);
            aq1[kc] = __builtin_bit_cast(bf16x8, w);
        }
    }

    const char* gK = wsK + (size_t)bh * 262144;
    const char* gV = wsV + (size_t)bh * 262144;
    const int go = tid * 16;

    auto STAGE = [&](int t) {
        const int bp = (t & 1) * 8192;
        const char* gk = gK + t * 8192;
        const char* gv = gV + t * 8192;
        char* lk = &Kl[0][0] + bp + wid * 1024;   // wave-uniform LDS base
        char* lv = &Vt[0][0] + bp + wid * 1024;
        gload16(gk + go, lk);
        gload16(gk + 4096 + go, lk + 4096);
        gload16(gv + go, lv);
        gload16(gv + 4096 + go, lv + 4096);
    };

    STAGE(0);

    float m0 = -1e30f, m1 = -1e30f;
    f32x4 lacc0 = (f32x4){0.f, 0.f, 0.f, 0.f};
    f32x4 lacc1 = (f32x4){0.f, 0.f, 0.f, 0.f};
    f32x4 oacc0[4], oacc1[4];
#pragma unroll
    for (int dt = 0; dt < 4; ++dt) {
        oacc0[dt] = (f32x4){0.f, 0.f, 0.f, 0.f};
        oacc1[dt] = (f32x4){0.f, 0.f, 0.f, 0.f};
    }

    const int cswz = (c & 7) << 4;
    const bf16x4 vone = {(short)0x3F80, (short)0x3F80, (short)0x3F80, (short)0x3F80};

    for (int t = 0; t < NT; ++t) {
        __syncthreads();               // drains DMA (vmcnt) + syncs block
        if (t + 1 < NT) STAGE(t + 1);
        const char* Kb = &Kl[0][0] + (t & 1) * 8192;
        const char* Vb = &Vt[0][0] + (t & 1) * 8192;

        // ---- QK^T swapped, both halves share each K fragment read ----
        f32x4 sac0[4], sac1[4];
        __builtin_amdgcn_s_setprio(1);
#pragma unroll
        for (int ks = 0; ks < 4; ++ks) {
            const char* rb = Kb + ((ks << 4) + c) * 128;
            bf16x8 kf0 = *(const bf16x8*)(rb + (((g << 4)     ) ^ cswz));
            bf16x8 kf1 = *(const bf16x8*)(rb + ((64 + (g << 4)) ^ cswz));
            f32x4 z0 = (f32x4){0.f, 0.f, 0.f, 0.f};
            z0 = __builtin_amdgcn_mfma_f32_16x16x32_bf16(kf0, aq0[0], z0, 0, 0, 0);
            z0 = __builtin_amdgcn_mfma_f32_16x16x32_bf16(kf1, aq0[1], z0, 0, 0, 0);
            sac0[ks] = z0;
            f32x4 z1 = (f32x4){0.f, 0.f, 0.f, 0.f};
            z1 = __builtin_amdgcn_mfma_f32_16x16x32_bf16(kf0, aq1[0], z1, 0, 0, 0);
            z1 = __builtin_amdgcn_mfma_f32_16x16x32_bf16(kf1, aq1[1], z1, 0, 0, 0);
            sac1[ks] = z1;
        }
        __builtin_amdgcn_s_setprio(0);

        // ---- online softmax, half 0 ----
        {
            float t0 = fmaxf(fmaxf(sac0[0][0], sac0[0][1]), fmaxf(sac0[0][2], sac0[0][3]));
            float t1 = fmaxf(fmaxf(sac0[1][0], sac0[1][1]), fmaxf(sac0[1][2], sac0[1][3]));
            float t2 = fmaxf(fmaxf(sac0[2][0], sac0[2][1]), fmaxf(sac0[2][2], sac0[2][3]));
            float t3 = fmaxf(fmaxf(sac0[3][0], sac0[3][1]), fmaxf(sac0[3][2], sac0[3][3]));
            const float ml = fmaxf(fmaxf(t0, t1), fmaxf(t2, t3));
            if (__any(ml > m0 + 10.0f)) {
                float vm = fmaxf(ml, __shfl_xor(ml, 16, 64));
                vm = fmaxf(vm, __shfl_xor(vm, 32, 64));
                const float mnew  = fmaxf(m0, vm);
                const float alpha = fexp2(m0 - mnew);
                m0 = mnew;
                lacc0 *= alpha;
#pragma unroll
                for (int dt = 0; dt < 4; ++dt) oacc0[dt] *= alpha;
            }
#pragma unroll
            for (int ks = 0; ks < 4; ++ks)
#pragma unroll
                for (int r = 0; r < 4; ++r)
                    sac0[ks][r] = fexp2(sac0[ks][r] - m0);
        }
        // ---- online softmax, half 1 ----
        {
            float t0 = fmaxf(fmaxf(sac1[0][0], sac1[0][1]), fmaxf(sac1[0][2], sac1[0][3]));
            float t1 = fmaxf(fmaxf(sac1[1][0], sac1[1][1]), fmaxf(sac1[1][2], sac1[1][3]));
            float t2 = fmaxf(fmaxf(sac1[2][0], sac1[2][1]), fmaxf(sac1[2][2], sac1[2][3]));
            float t3 = fmaxf(fmaxf(sac1[3][0], sac1[3][1]), fmaxf(sac1[3][2], sac1[3][3]));
            const float ml = fmaxf(fmaxf(t0, t1), fmaxf(t2, t3));
            if (__any(ml > m1 + 10.0f)) {
                float vm = fmaxf(ml, __shfl_xor(ml, 16, 64));
                vm = fmaxf(vm, __shfl_xor(vm, 32, 64));
                const float mnew  = fmaxf(m1, vm);
                const float alpha = fexp2(m1 - mnew);
                m1 = mnew;
                lacc1 *= alpha;
#pragma unroll
                for (int dt = 0; dt < 4; ++dt) oacc1[dt] *= alpha;
            }
#pragma unroll
            for (int ks = 0; ks < 4; ++ks)
#pragma unroll
                for (int r = 0; r < 4; ++r)
                    sac1[ks][r] = fexp2(sac1[ks][r] - m1);
        }

        // ---- pack + PV + l-sum; each V fragment read feeds both halves ----
        __builtin_amdgcn_s_setprio(1);
#pragma unroll
        for (int ks = 0; ks < 4; ++ks) {
            i32x2 pp0, pp1;
            pp0[0] = (int)pkc(sac0[ks][0], sac0[ks][1]);
            pp0[1] = (int)pkc(sac0[ks][2], sac0[ks][3]);
            pp1[0] = (int)pkc(sac1[ks][0], sac1[ks][1]);
            pp1[1] = (int)pkc(sac1[ks][2], sac1[ks][3]);
            const bf16x4 pf0 = __builtin_bit_cast(bf16x4, pp0);
            const bf16x4 pf1 = __builtin_bit_cast(bf16x4, pp1);
            lacc0 = pv_mfma16(vone, pf0, lacc0);
            lacc1 = pv_mfma16(vone, pf1, lacc1);
#pragma unroll
            for (int dt = 0; dt < 4; ++dt) {
                const i32x2 vv = *(const i32x2*)(Vb + ((dt << 4) + c) * 128 +
                                   (((ks << 5) + (g << 3)) ^ (c << 3)));
                const bf16x4 vf = __builtin_bit_cast(bf16x4, vv);
                oacc0[dt] = pv_mfma16(vf, pf0, oacc0[dt]);
                oacc1[dt] = pv_mfma16(vf, pf1, oacc1[dt]);
            }
        }
        __builtin_amdgcn_s_setprio(0);
    }

    // ---- epilogue: both halves ----
    const float inv0 = 1.0f / lacc0[0];
    const float inv1 = 1.0f / lacc1[0];
    float* op0 = out + (((size_t)b * Tq + qrow) * Hq + h) * Dq;
    float* op1 = op0 + 16 * Hq * Dq;
#pragma unroll
    for (int dt = 0; dt < 4; ++dt) {
        f32x4 o0 = oacc0[dt] * inv0;
        *(f32x4*)(op0 + (dt << 4) + (g << 2)) = o0;
        f32x4 o1 = oacc1[dt] * inv1;
        *(f32x4*)(op1 + (dt << 4) + (g << 2)) = o1;
    }
}

// ---------------- fallback (round-8 single-q-tile path) if ws too small ----------------
__global__ __launch_bounds__(256, 4) void fattn_v4(
    const float* __restrict__ q, const float* __restrict__ kvp,
    float* __restrict__ out)
{
    __shared__ __align__(16) short Kl[2][KVBLK * 64];
    __shared__ __align__(16) short Vt[2][64 * KVBLK];

    const int tid = threadIdx.x;
    const int c   = tid & 15;
    const int g   = (tid >> 4) & 3;
    const int wid = tid >> 6;

    const int lbid = ((blockIdx.x & 7) << 8) | (blockIdx.x >> 3);
    const int qt = lbid & 31;
    const int bh = lbid >> 5;
    const int b  = bh >> 4;
    const int h  = bh & 15;

    const float QSCL = 0.125f * 1.4426950408889634f;

    const int qrow = (qt << 6) + (wid << 4) + c;
    const float* qp = q + (((size_t)b * Tq + qrow) * Hq + h) * Dq;
    bf16x8 aq[2];
#pragma unroll
    for (int kc = 0; kc < 2; ++kc) {
        f32x4 f0 = *(const f32x4*)(qp + kc * 32 + g * 8);
        f32x4 f1 = *(const f32x4*)(qp + kc * 32 + g * 8 + 4);
        i32x4 w;
        w[0] = (int)pkc(f0[0] * QSCL, f0[1] * QSCL);
        w[1] = (int)pkc(f0[2] * QSCL, f0[3] * QSCL);
        w[2] = (int)pkc(f1[0] * QSCL, f1[1] * QSCL);
        w[3] = (int)pkc(f1[2] * QSCL, f1[3] * QSCL);
        aq[kc] = __builtin_bit_cast(bf16x8, w);
    }

    const int ksr = tid >> 2;
    const int ksd = (tid & 3) << 4;
    const int vw4 = tid >> 4;
    const int vd0 = (tid & 15) << 2;

    const float* kbase = kvp + (size_t)b * Sq * 2 * Hq * Dq + h * Dq;
    f32x4 kr0, kr1, kr2, kr3, vr0, vr1, vr2, vr3;

    auto ISSUE = [&](int t) {
        const float* kp = kbase + (size_t)(t * KVBLK + ksr) * 2048 + ksd;
        kr0 = *(const f32x4*)(kp);
        kr1 = *(const f32x4*)(kp + 4);
        kr2 = *(const f32x4*)(kp + 8);
        kr3 = *(const f32x4*)(kp + 12);
        const float* vp = kbase + (size_t)(t * KVBLK + (vw4 << 2)) * 2048 + 1024 + vd0;
        vr0 = *(const f32x4*)(vp);
        vr1 = *(const f32x4*)(vp + 2048);
        vr2 = *(const f32x4*)(vp + 4096);
        vr3 = *(const f32x4*)(vp + 6144);
    };
    auto WRITE = [&](int t) {
        const int bp = t & 1;
        char* Kb = (char*)Kl[bp];
        char* Vb = (char*)Vt[bp];
        const int kswz = (ksr & 7) << 4;
        i32x4 w;
        w[0] = (int)pkc(kr0[0], kr0[1]); w[1] = (int)pkc(kr0[2], kr0[3]);
        w[2] = (int)pkc(kr1[0], kr1[1]); w[3] = (int)pkc(kr1[2], kr1[3]);
        *(bf16x8*)(Kb + ksr * 128 + (((ksd << 1)     ) ^ kswz)) = __builtin_bit_cast(bf16x8, w);
        w[0] = (int)pkc(kr2[0], kr2[1]); w[1] = (int)pkc(kr2[2], kr2[3]);
        w[2] = (int)pkc(kr3[0], kr3[1]); w[3] = (int)pkc(kr3[2], kr3[3]);
        *(bf16x8*)(Kb + ksr * 128 + (((ksd << 1) + 16) ^ kswz)) = __builtin_bit_cast(bf16x8, w);
#pragma unroll
        for (int j = 0; j < 4; ++j) {
            i32x2 t2;
            t2[0] = (int)pkc(vr0[j], vr1[j]);
            t2[1] = (int)pkc(vr2[j], vr3[j]);
            const int row = vd0 + j;
            *(i32x2*)(Vb + row * 128 + ((vw4 << 3) ^ ((row & 7) << 4))) = t2;
        }
    };

    ISSUE(0);
    WRITE(0);

    float m_r = -1e30f, l_r = 0.f;
    f32x4 oacc[4];
#pragma unroll
    for (int dt = 0; dt < 4; ++dt) oacc[dt] = (f32x4){0.f, 0.f, 0.f, 0.f};
    const int cswz = (c & 7) << 4;

    for (int t = 0; t < NT; ++t) {
        __syncthreads();
        const char* Kb = (const char*)Kl[t & 1];
        const char* Vb = (const char*)Vt[t & 1];

        f32x4 sac[4];
#pragma unroll
        for (int ks = 0; ks < 4; ++ks) {
            const char* rb = Kb + ((ks << 4) + c) * 128;
            bf16x8 kf0 = *(const bf16x8*)(rb + (((g << 4)     ) ^ cswz));
            bf16x8 kf1 = *(const bf16x8*)(rb + ((64 + (g << 4)) ^ cswz));
            f32x4 z = (f32x4){0.f, 0.f, 0.f, 0.f};
            z = __builtin_amdgcn_mfma_f32_16x16x32_bf16(kf0, aq[0], z, 0, 0, 0);
            z = __builtin_amdgcn_mfma_f32_16x16x32_bf16(kf1, aq[1], z, 0, 0, 0);
            sac[ks] = z;
        }
        ISSUE(t + 1 < NT ? t + 1 : NT - 1);

        float vmax = sac[0][0];
#pragma unroll
        for (int ks = 0; ks < 4; ++ks)
#pragma unroll
            for (int r = 0; r < 4; ++r) vmax = fmaxf(vmax, sac[ks][r]);
        vmax = fmaxf(vmax, __shfl_xor(vmax, 16, 64));
        vmax = fmaxf(vmax, __shfl_xor(vmax, 32, 64));
        if (__any(vmax > m_r + 10.0f)) {
            const float mnew  = fmaxf(m_r, vmax);
            const float alpha = exp2f(m_r - mnew);
            m_r = mnew;
            l_r *= alpha;
#pragma unroll
            for (int dt = 0; dt < 4; ++dt) oacc[dt] *= alpha;
        }
        float ssum = 0.f;
#pragma unroll
        for (int ks = 0; ks < 4; ++ks)
#pragma unroll
            for (int r = 0; r < 4; ++r) {
                const float p = exp2f(sac[ks][r] - m_r);
                sac[ks][r] = p;
                ssum += p;
            }
        ssum += __shfl_xor(ssum, 16, 64);
        ssum += __shfl_xor(ssum, 32, 64);
        l_r += ssum;

#pragma unroll
        for (int ks = 0; ks < 4; ++ks) {
            i32x2 pp;
            pp[0] = (int)pkc(sac[ks][0], sac[ks][1]);
            pp[1] = (int)pkc(sac[ks][2], sac[ks][3]);
            const bf16x4 pf = __builtin_bit_cast(bf16x4, pp);
#pragma unroll
            for (int dt = 0; dt < 4; ++dt) {
                const i32x2 vv = *(const i32x2*)(Vb + ((dt << 4) + c) * 128 +
                                   (((ks << 5) + (g << 3)) ^ cswz));
                const bf16x4 vf = __builtin_bit_cast(bf16x4, vv);
                oacc[dt] = pv_mfma16(vf, pf, oacc[dt]);
            }
        }
        WRITE(t + 1);
    }

    const float inv = 1.0f / l_r;
    float* op = out + (((size_t)b * Tq + qrow) * Hq + h) * Dq;
#pragma unroll
    for (int dt = 0; dt < 4; ++dt) {
        f32x4 o = oacc[dt] * inv;
        *(f32x4*)(op + (dt << 4) + (g << 2)) = o;
    }
}

extern "C" void kernel_launch(void* const* d_in, const int* in_sizes, int n_in,
                              void* d_out, int out_size, void* d_ws, size_t ws_size,
                              hipStream_t stream) {
    const float* q  = (const float*)d_in[0];
    const float* kv = (const float*)d_in[1];
    float* out = (float*)d_out;
    if (ws_size >= (size_t)33554432) {
        char* wsK = (char*)d_ws;
        char* wsV = wsK + 16777216;
        prepass<<<dim3(16384), dim3(256), 0, stream>>>(kv, wsK, wsV);
        fattn_main<<<dim3(1024), dim3(256), 0, stream>>>(q, wsK, wsV, out);
    } else {
        fattn_v4<<<dim3(2048), dim3(256), 0, stream>>>(q, kv, out);
    }
}

// Round 10
// 118.094 us; speedup vs baseline: 2.6635x; 1.0713x over previous
//
#include <hip/hip_runtime.h>
#include <hip/hip_bf16.h>

#define Bq 4
#define Tq 2048
#define Sq 2048
#define Hq 16
#define Dq 64
#define KVBLK 64
#define NT (Sq / KVBLK)

typedef short bf16x8 __attribute__((ext_vector_type(8)));
typedef short bf16x4 __attribute__((ext_vector_type(4)));
typedef float f32x4 __attribute__((ext_vector_type(4)));
typedef int   i32x4 __attribute__((ext_vector_type(4)));
typedef int   i32x2 __attribute__((ext_vector_type(2)));
typedef unsigned int u32;

// Device-pass-only builtins (host pass gets parse-only stubs).
#if defined(__HIP_DEVICE_COMPILE__)
#if __has_builtin(__builtin_amdgcn_mfma_f32_16x16x16bf16_1k)
#define HAVE_MFMA16 1
#endif
#if __has_builtin(__builtin_amdgcn_exp2f)
#define HAVE_EXP2 1
#endif
#endif
#ifndef HAVE_MFMA16
#define HAVE_MFMA16 0
#endif
#ifndef HAVE_EXP2
#define HAVE_EXP2 0
#endif

static __device__ __forceinline__ f32x4 pv_mfma16(bf16x4 vf, bf16x4 pf, f32x4 acc) {
#if HAVE_MFMA16
    return __builtin_amdgcn_mfma_f32_16x16x16bf16_1k(vf, pf, acc, 0, 0, 0);
#else
    return acc;   // host-pass stub only
#endif
}

static __device__ __forceinline__ float fexp2(float x) {
#if HAVE_EXP2
    return __builtin_amdgcn_exp2f(x);   // raw v_exp_f32 (2^x)
#else
    return exp2f(x);
#endif
}

// float pair -> packed bf16 (RNE), low short = a. The HIP intrinsic owns the
// HW cvt_pk operand semantics (hand-rolled asm in r7 had them wrong).
static __device__ __forceinline__ u32 pk2f(float a, float b) {
#if defined(__HIP_DEVICE_COMPILE__)
    __hip_bfloat162 h = __float22bfloat162_rn(make_float2(a, b));
    u32 r; __builtin_memcpy(&r, &h, 4);
    return r;
#else
    return 0u;    // host-pass stub only
#endif
}

static __device__ __forceinline__ u32 pkc(float a, float b) {
    // integer RNE pack (prepass + fallback; proven r1-r9)
    u32 ua = __float_as_uint(a); ua += 0x7fffu + ((ua >> 16) & 1u);
    u32 ub = __float_as_uint(b); ub += 0x7fffu + ((ub >> 16) & 1u);
    return (ua >> 16) | (ub & 0xffff0000u);
}

static __device__ __forceinline__ void gload16(const void* g, void* l) {
    __builtin_amdgcn_global_load_lds(
        (const __attribute__((address_space(1))) u32*)g,
        (__attribute__((address_space(3))) u32*)l, 16, 0, 0);
}

// max of 16 values in max3-fusable shape (8 instrs when fused)
static __device__ __forceinline__ float max16(const f32x4* s) {
    float t0 = fmaxf(fmaxf(s[0][0], s[0][1]), s[0][2]);
    float t1 = fmaxf(fmaxf(s[0][3], s[1][0]), s[1][1]);
    float t2 = fmaxf(fmaxf(s[1][2], s[1][3]), s[2][0]);
    float t3 = fmaxf(fmaxf(s[2][1], s[2][2]), s[2][3]);
    float t4 = fmaxf(fmaxf(s[3][0], s[3][1]), s[3][2]);
    float u0 = fmaxf(fmaxf(t0, t1), s[3][3]);
    float u1 = fmaxf(fmaxf(t2, t3), t4);
    return fmaxf(u0, u1);
}

// ---------------- pre-pass: kv fp32 -> bf16 LDS-tile images in ws ----------------
__global__ __launch_bounds__(256) void prepass(const float* __restrict__ kvp,
                                               char* __restrict__ wsK,
                                               char* __restrict__ wsV)
{
    if (blockIdx.x < 8192) {
        const int t = blockIdx.x * 256 + threadIdx.x;
        const int dq = t & 15, h = (t >> 4) & 15, s = (t >> 8) & 2047, b = t >> 19;
        const float* p = kvp + ((size_t)(b * 2048 + s)) * 2048 + h * 64 + dq * 4;
        const f32x4 f = *(const f32x4*)p;
        i32x2 w; w[0] = (int)pkc(f[0], f[1]); w[1] = (int)pkc(f[2], f[3]);
        char* d = wsK + (size_t)(b * 16 + h) * 262144 + (s >> 6) * 8192
                + (s & 63) * 128 + ((dq * 8) ^ ((s & 7) << 4));
        *(i32x2*)d = w;
    } else {
        const int t2 = (blockIdx.x - 8192) * 256 + threadIdx.x;
        const int dd = t2 & 63, h = (t2 >> 6) & 15, sq = (t2 >> 10) & 511, b = t2 >> 19;
        const float* p = kvp + ((size_t)(b * 2048 + sq * 4)) * 2048 + 1024 + h * 64 + dd;
        const float v0 = p[0], v1 = p[2048], v2 = p[4096], v3 = p[6144];
        i32x2 w; w[0] = (int)pkc(v0, v1); w[1] = (int)pkc(v2, v3);
        char* d = wsV + (size_t)(b * 16 + h) * 262144 + (sq >> 4) * 8192
                + dd * 128 + (((sq & 15) * 8) ^ ((dd & 15) << 3));
        *(i32x2*)d = w;
    }
}

// ---------------- main kernel: 32 q-rows/wave, low-VALU softmax ----------------
__global__ __launch_bounds__(256, 4) void fattn_main(
    const float* __restrict__ q, const char* __restrict__ wsK,
    const char* __restrict__ wsV, float* __restrict__ out)
{
    __shared__ __align__(16) char Kl[2][8192];
    __shared__ __align__(16) char Vt[2][8192];

    const int tid = threadIdx.x;
    const int c   = tid & 15;
    const int g   = (tid >> 4) & 3;
    const int wid = tid >> 6;

    // XCD-aware swizzle (1024 blocks = 8 XCDs x 128)
    const int lbid = ((blockIdx.x & 7) << 7) | (blockIdx.x >> 3);
    const int qt = lbid & 15;            // 16 q-tiles of 128 rows
    const int bh = lbid >> 4;
    const int b  = bh >> 4;
    const int h  = bh & 15;

    const float QSCL = 0.125f * 1.4426950408889634f;   // 1/sqrt(D) * log2(e)

    // ---- Two Q fragment sets: rows qrow (half0) and qrow+16 (half1) ----
    const int qrow = (qt << 7) + (wid << 5) + c;
    const float* qp0 = q + (((size_t)b * Tq + qrow) * Hq + h) * Dq;
    bf16x8 aq0[2], aq1[2];
#pragma unroll
    for (int kc = 0; kc < 2; ++kc) {
        {
            f32x4 f0 = *(const f32x4*)(qp0 + kc * 32 + g * 8);
            f32x4 f1 = *(const f32x4*)(qp0 + kc * 32 + g * 8 + 4);
            i32x4 w;
            w[0] = (int)pk2f(f0[0] * QSCL, f0[1] * QSCL);
            w[1] = (int)pk2f(f0[2] * QSCL, f0[3] * QSCL);
            w[2] = (int)pk2f(f1[0] * QSCL, f1[1] * QSCL);
            w[3] = (int)pk2f(f1[2] * QSCL, f1[3] * QSCL);
            aq0[kc] = __builtin_bit_cast(bf16x8, w);
        }
        {
            const float* qp1 = qp0 + 16 * Hq * Dq;
            f32x4 f0 = *(const f32x4*)(qp1 + kc * 32 + g * 8);
            f32x4 f1 = *(const f32x4*)(qp1 + kc * 32 + g * 8 + 4);
            i32x4 w;
            w[0] = (int)pk2f(f0[0] * QSCL, f0[1] * QSCL);
            w[1] = (int)pk2f(f0[2] * QSCL, f0[3] * QSCL);
            w[2] = (int)pk2f(f1[0] * QSCL, f1[1] * QSCL);
            w[3] = (int)pk2f(f1[2] * QSCL, f1[3] * QSCL);
            aq1[kc] = __builtin_bit_cast(bf16x8, w);
        }
    }

    const char* gK = wsK + (size_t)bh * 262144;
    const char* gV = wsV + (size_t)bh * 262144;
    const int go = tid * 16;

    auto STAGE = [&](int t) {
        const int bp = (t & 1) * 8192;
        const char* gk = gK + t * 8192;
        const char* gv = gV + t * 8192;
        char* lk = &Kl[0][0] + bp + wid * 1024;   // wave-uniform LDS base
        char* lv = &Vt[0][0] + bp + wid * 1024;
        gload16(gk + go, lk);
        gload16(gk + 4096 + go, lk + 4096);
        gload16(gv + go, lv);
        gload16(gv + 4096 + go, lv + 4096);
    };

    STAGE(0);

    float m0 = -1e30f, m1 = -1e30f;
    f32x4 lacc0 = (f32x4){0.f, 0.f, 0.f, 0.f};
    f32x4 lacc1 = (f32x4){0.f, 0.f, 0.f, 0.f};
    f32x4 oacc0[4], oacc1[4];
#pragma unroll
    for (int dt = 0; dt < 4; ++dt) {
        oacc0[dt] = (f32x4){0.f, 0.f, 0.f, 0.f};
        oacc1[dt] = (f32x4){0.f, 0.f, 0.f, 0.f};
    }

    const int cswz = (c & 7) << 4;
    const bf16x4 vone = {(short)0x3F80, (short)0x3F80, (short)0x3F80, (short)0x3F80};

#pragma unroll 2
    for (int t = 0; t < NT; ++t) {
        __syncthreads();               // drains DMA (vmcnt) + syncs block
        if (t + 1 < NT) STAGE(t + 1);
        const char* Kb = &Kl[0][0] + (t & 1) * 8192;
        const char* Vb = &Vt[0][0] + (t & 1) * 8192;

        // ---- QK^T swapped, both halves share each K fragment read ----
        f32x4 sac0[4], sac1[4];
        __builtin_amdgcn_s_setprio(1);
#pragma unroll
        for (int ks = 0; ks < 4; ++ks) {
            const char* rb = Kb + ((ks << 4) + c) * 128;
            bf16x8 kf0 = *(const bf16x8*)(rb + (((g << 4)     ) ^ cswz));
            bf16x8 kf1 = *(const bf16x8*)(rb + ((64 + (g << 4)) ^ cswz));
            f32x4 z0 = (f32x4){0.f, 0.f, 0.f, 0.f};
            z0 = __builtin_amdgcn_mfma_f32_16x16x32_bf16(kf0, aq0[0], z0, 0, 0, 0);
            z0 = __builtin_amdgcn_mfma_f32_16x16x32_bf16(kf1, aq0[1], z0, 0, 0, 0);
            sac0[ks] = z0;
            f32x4 z1 = (f32x4){0.f, 0.f, 0.f, 0.f};
            z1 = __builtin_amdgcn_mfma_f32_16x16x32_bf16(kf0, aq1[0], z1, 0, 0, 0);
            z1 = __builtin_amdgcn_mfma_f32_16x16x32_bf16(kf1, aq1[1], z1, 0, 0, 0);
            sac1[ks] = z1;
        }
        __builtin_amdgcn_s_setprio(0);

        // ---- per-lane maxes (max3-fusable trees) ----
        const float ml0 = max16(sac0);
        const float ml1 = max16(sac1);

        // T13 defer-max: rescale only when max grew materially (P <= 2^10)
        if (__any(ml0 > m0 + 10.0f)) {
            float vm = fmaxf(ml0, __shfl_xor(ml0, 16, 64));
            vm = fmaxf(vm, __shfl_xor(vm, 32, 64));
            const float mnew  = fmaxf(m0, vm);
            const float alpha = fexp2(m0 - mnew);
            m0 = mnew;
            lacc0 *= alpha;
#pragma unroll
            for (int dt = 0; dt < 4; ++dt) oacc0[dt] *= alpha;
        }
        if (__any(ml1 > m1 + 10.0f)) {
            float vm = fmaxf(ml1, __shfl_xor(ml1, 16, 64));
            vm = fmaxf(vm, __shfl_xor(vm, 32, 64));
            const float mnew  = fmaxf(m1, vm);
            const float alpha = fexp2(m1 - mnew);
            m1 = mnew;
            lacc1 *= alpha;
#pragma unroll
            for (int dt = 0; dt < 4; ++dt) oacc1[dt] *= alpha;
        }

        // ---- P = 2^(s - m), both halves interleaved for trans-pipe ILP ----
#pragma unroll
        for (int ks = 0; ks < 4; ++ks)
#pragma unroll
            for (int r = 0; r < 4; ++r) {
                sac0[ks][r] = fexp2(sac0[ks][r] - m0);
                sac1[ks][r] = fexp2(sac1[ks][r] - m1);
            }

        // ---- pack (cvt_pk) + PV + l-sum; each V read feeds both halves ----
        __builtin_amdgcn_s_setprio(1);
#pragma unroll
        for (int ks = 0; ks < 4; ++ks) {
            i32x2 pp0, pp1;
            pp0[0] = (int)pk2f(sac0[ks][0], sac0[ks][1]);
            pp0[1] = (int)pk2f(sac0[ks][2], sac0[ks][3]);
            pp1[0] = (int)pk2f(sac1[ks][0], sac1[ks][1]);
            pp1[1] = (int)pk2f(sac1[ks][2], sac1[ks][3]);
            const bf16x4 pf0 = __builtin_bit_cast(bf16x4, pp0);
            const bf16x4 pf1 = __builtin_bit_cast(bf16x4, pp1);
            lacc0 = pv_mfma16(vone, pf0, lacc0);
            lacc1 = pv_mfma16(vone, pf1, lacc1);
#pragma unroll
            for (int dt = 0; dt < 4; ++dt) {
                const i32x2 vv = *(const i32x2*)(Vb + ((dt << 4) + c) * 128 +
                                   (((ks << 5) + (g << 3)) ^ (c << 3)));
                const bf16x4 vf = __builtin_bit_cast(bf16x4, vv);
                oacc0[dt] = pv_mfma16(vf, pf0, oacc0[dt]);
                oacc1[dt] = pv_mfma16(vf, pf1, oacc1[dt]);
            }
        }
        __builtin_amdgcn_s_setprio(0);
    }

    // ---- epilogue: both halves ----
    const float inv0 = 1.0f / lacc0[0];
    const float inv1 = 1.0f / lacc1[0];
    float* op0 = out + (((size_t)b * Tq + qrow) * Hq + h) * Dq;
    float* op1 = op0 + 16 * Hq * Dq;
#pragma unroll
    for (int dt = 0; dt < 4; ++dt) {
        f32x4 o0 = oacc0[dt] * inv0;
        *(f32x4*)(op0 + (dt << 4) + (g << 2)) = o0;
        f32x4 o1 = oacc1[dt] * inv1;
        *(f32x4*)(op1 + (dt << 4) + (g << 2)) = o1;
    }
}

// ---------------- fallback (round-8 single-q-tile path) if ws too small ----------------
__global__ __launch_bounds__(256, 4) void fattn_v4(
    const float* __restrict__ q, const float* __restrict__ kvp,
    float* __restrict__ out)
{
    __shared__ __align__(16) short Kl[2][KVBLK * 64];
    __shared__ __align__(16) short Vt[2][64 * KVBLK];

    const int tid = threadIdx.x;
    const int c   = tid & 15;
    const int g   = (tid >> 4) & 3;
    const int wid = tid >> 6;

    const int lbid = ((blockIdx.x & 7) << 8) | (blockIdx.x >> 3);
    const int qt = lbid & 31;
    const int bh = lbid >> 5;
    const int b  = bh >> 4;
    const int h  = bh & 15;

    const float QSCL = 0.125f * 1.4426950408889634f;

    const int qrow = (qt << 6) + (wid << 4) + c;
    const float* qp = q + (((size_t)b * Tq + qrow) * Hq + h) * Dq;
    bf16x8 aq[2];
#pragma unroll
    for (int kc = 0; kc < 2; ++kc) {
        f32x4 f0 = *(const f32x4*)(qp + kc * 32 + g * 8);
        f32x4 f1 = *(const f32x4*)(qp + kc * 32 + g * 8 + 4);
        i32x4 w;
        w[0] = (int)pkc(f0[0] * QSCL, f0[1] * QSCL);
        w[1] = (int)pkc(f0[2] * QSCL, f0[3] * QSCL);
        w[2] = (int)pkc(f1[0] * QSCL, f1[1] * QSCL);
        w[3] = (int)pkc(f1[2] * QSCL, f1[3] * QSCL);
        aq[kc] = __builtin_bit_cast(bf16x8, w);
    }

    const int ksr = tid >> 2;
    const int ksd = (tid & 3) << 4;
    const int vw4 = tid >> 4;
    const int vd0 = (tid & 15) << 2;

    const float* kbase = kvp + (size_t)b * Sq * 2 * Hq * Dq + h * Dq;
    f32x4 kr0, kr1, kr2, kr3, vr0, vr1, vr2, vr3;

    auto ISSUE = [&](int t) {
        const float* kp = kbase + (size_t)(t * KVBLK + ksr) * 2048 + ksd;
        kr0 = *(const f32x4*)(kp);
        kr1 = *(const f32x4*)(kp + 4);
        kr2 = *(const f32x4*)(kp + 8);
        kr3 = *(const f32x4*)(kp + 12);
        const float* vp = kbase + (size_t)(t * KVBLK + (vw4 << 2)) * 2048 + 1024 + vd0;
        vr0 = *(const f32x4*)(vp);
        vr1 = *(const f32x4*)(vp + 2048);
        vr2 = *(const f32x4*)(vp + 4096);
        vr3 = *(const f32x4*)(vp + 6144);
    };
    auto WRITE = [&](int t) {
        const int bp = t & 1;
        char* Kb = (char*)Kl[bp];
        char* Vb = (char*)Vt[bp];
        const int kswz = (ksr & 7) << 4;
        i32x4 w;
        w[0] = (int)pkc(kr0[0], kr0[1]); w[1] = (int)pkc(kr0[2], kr0[3]);
        w[2] = (int)pkc(kr1[0], kr1[1]); w[3] = (int)pkc(kr1[2], kr1[3]);
        *(bf16x8*)(Kb + ksr * 128 + (((ksd << 1)     ) ^ kswz)) = __builtin_bit_cast(bf16x8, w);
        w[0] = (int)pkc(kr2[0], kr2[1]); w[1] = (int)pkc(kr2[2], kr2[3]);
        w[2] = (int)pkc(kr3[0], kr3[1]); w[3] = (int)pkc(kr3[2], kr3[3]);
        *(bf16x8*)(Kb + ksr * 128 + (((ksd << 1) + 16) ^ kswz)) = __builtin_bit_cast(bf16x8, w);
#pragma unroll
        for (int j = 0; j < 4; ++j) {
            i32x2 t2;
            t2[0] = (int)pkc(vr0[j], vr1[j]);
            t2[1] = (int)pkc(vr2[j], vr3[j]);
            const int row = vd0 + j;
            *(i32x2*)(Vb + row * 128 + ((vw4 << 3) ^ ((row & 7) << 4))) = t2;
        }
    };

    ISSUE(0);
    WRITE(0);

    float m_r = -1e30f, l_r = 0.f;
    f32x4 oacc[4];
#pragma unroll
    for (int dt = 0; dt < 4; ++dt) oacc[dt] = (f32x4){0.f, 0.f, 0.f, 0.f};
    const int cswz = (c & 7) << 4;

    for (int t = 0; t < NT; ++t) {
        __syncthreads();
        const char* Kb = (const char*)Kl[t & 1];
        const char* Vb = (const char*)Vt[t & 1];

        f32x4 sac[4];
#pragma unroll
        for (int ks = 0; ks < 4; ++ks) {
            const char* rb = Kb + ((ks << 4) + c) * 128;
            bf16x8 kf0 = *(const bf16x8*)(rb + (((g << 4)     ) ^ cswz));
            bf16x8 kf1 = *(const bf16x8*)(rb + ((64 + (g << 4)) ^ cswz));
            f32x4 z = (f32x4){0.f, 0.f, 0.f, 0.f};
            z = __builtin_amdgcn_mfma_f32_16x16x32_bf16(kf0, aq[0], z, 0, 0, 0);
            z = __builtin_amdgcn_mfma_f32_16x16x32_bf16(kf1, aq[1], z, 0, 0, 0);
            sac[ks] = z;
        }
        ISSUE(t + 1 < NT ? t + 1 : NT - 1);

        float vmax = sac[0][0];
#pragma unroll
        for (int ks = 0; ks < 4; ++ks)
#pragma unroll
            for (int r = 0; r < 4; ++r) vmax = fmaxf(vmax, sac[ks][r]);
        vmax = fmaxf(vmax, __shfl_xor(vmax, 16, 64));
        vmax = fmaxf(vmax, __shfl_xor(vmax, 32, 64));
        if (__any(vmax > m_r + 10.0f)) {
            const float mnew  = fmaxf(m_r, vmax);
            const float alpha = exp2f(m_r - mnew);
            m_r = mnew;
            l_r *= alpha;
#pragma unroll
            for (int dt = 0; dt < 4; ++dt) oacc[dt] *= alpha;
        }
        float ssum = 0.f;
#pragma unroll
        for (int ks = 0; ks < 4; ++ks)
#pragma unroll
            for (int r = 0; r < 4; ++r) {
                const float p = exp2f(sac[ks][r] - m_r);
                sac[ks][r] = p;
                ssum += p;
            }
        ssum += __shfl_xor(ssum, 16, 64);
        ssum += __shfl_xor(ssum, 32, 64);
        l_r += ssum;

#pragma unroll
        for (int ks = 0; ks < 4; ++ks) {
            i32x2 pp;
            pp[0] = (int)pkc(sac[ks][0], sac[ks][1]);
            pp[1] = (int)pkc(sac[ks][2], sac[ks][3]);
            const bf16x4 pf = __builtin_bit_cast(bf16x4, pp);
#pragma unroll
            for (int dt = 0; dt < 4; ++dt) {
                const i32x2 vv = *(const i32x2*)(Vb + ((dt << 4) + c) * 128 +
                                   (((ks << 5) + (g << 3)) ^ cswz));
                const bf16x4 vf = __builtin_bit_cast(bf16x4, vv);
                oacc[dt] = pv_mfma16(vf, pf, oacc[dt]);
            }
        }
        WRITE(t + 1);
    }

    const float inv = 1.0f / l_r;
    float* op = out + (((size_t)b * Tq + qrow) * Hq + h) * Dq;
#pragma unroll
    for (int dt = 0; dt < 4; ++dt) {
        f32x4 o = oacc[dt] * inv;
        *(f32x4*)(op + (dt << 4) + (g << 2)) = o;
    }
}

extern "C" void kernel_launch(void* const* d_in, const int* in_sizes, int n_in,
                              void* d_out, int out_size, void* d_ws, size_t ws_size,
                              hipStream_t stream) {
    const float* q  = (const float*)d_in[0];
    const float* kv = (const float*)d_in[1];
    float* out = (float*)d_out;
    if (ws_size >= (size_t)33554432) {
        char* wsK = (char*)d_ws;
        char* wsV = wsK + 16777216;
        prepass<<<dim3(16384), dim3(256), 0, stream>>>(kv, wsK, wsV);
        fattn_main<<<dim3(1024), dim3(256), 0, stream>>>(q, wsK, wsV, out);
    } else {
        fattn_v4<<<dim3(2048), dim3(256), 0, stream>>>(q, kv, out);
    }
}